// Round 1
// 845.526 us; speedup vs baseline: 1.1266x; 1.1266x over previous
//
#include <hip/hip_runtime.h>
#include <stdint.h>

typedef unsigned short ushort_t;
typedef __bf16 bf16x8 __attribute__((ext_vector_type(8)));
typedef float f32x4 __attribute__((ext_vector_type(4)));
typedef unsigned short us8 __attribute__((ext_vector_type(8)));
typedef unsigned short us4 __attribute__((ext_vector_type(4)));

#define BB 8
#define TT 2048
#define CC 1024
#define NEG_INF_F (-4294967295.0f)

__device__ __forceinline__ float bf2f(ushort_t u) {
    union { unsigned int i; float f; } v; v.i = ((unsigned int)u) << 16; return v.f;
}
__device__ __forceinline__ ushort_t f2bf(float f) {   // RNE
    union { float f; unsigned int i; } v; v.f = f;
    unsigned int r = (v.i + 0x7fffu + ((v.i >> 16) & 1u)) >> 16;
    return (ushort_t)r;
}

// async global->LDS, 16B per lane. LDS dest = wave-uniform base + lane*16 (m104).
__device__ __forceinline__ void gl_lds16(const ushort_t* g, ushort_t* l)
{
    __builtin_amdgcn_global_load_lds(
        (__attribute__((address_space(1))) void*)(void*)(g),
        (__attribute__((address_space(3))) void*)(l),
        16, 0, 0);
}

// ---------------- MFMA GEMM:  C = epi(alpha * A @ B^T), bf16 inputs ----------------
// A: [M,K] row-major bf16; Bm: [N,K] row-major bf16. C row-major, f32 or bf16.
// Batched via blockIdx.z (strides in elems; sCbBytes in bytes).
// epi: 0=none 1=relu 2=relu*aux[col] 3=+aux[col] 4=relu(+aux[col]) 5=+aux[z,row,col].
//
// m97-structure: 128x128 tile, BK=64, 4 waves (2x2), global_load_lds dwordx4
// staging, single LDS buffer, 2 barriers per K-step.
// LDS layout: linear [128][64] bf16 with 16B-slot XOR swizzle applied on BOTH
// sides (rule #21): source k-slot is pre-XORed so gload_lds's linear write
// lands the swizzled layout; ds_read applies the same XOR. slot' = slot ^ (row&7)
// -> frag reads are 2-way bank aliased (free, m136) instead of 8/16-way.
#define TM 128
#define TN 128
#define BK 64

__global__ __launch_bounds__(256) void gemm_bt(
    const ushort_t* __restrict__ Am, long sAe, int lda,
    const ushort_t* __restrict__ Bm, long sBe, int ldb,
    void* __restrict__ Cm, long sCbBytes, int ldc, int outF32,
    int K, float alpha, int epi,
    const float* __restrict__ aux, long sAuxb, int ldaux)
{
    __shared__ ushort_t aT[TM * BK];   // 16 KiB
    __shared__ ushort_t bT[TN * BK];   // 16 KiB
    const int z = blockIdx.z;
    const ushort_t* A = Am + (long)z * sAe;
    const ushort_t* B = Bm + (long)z * sBe;
    char* Cb = (char*)Cm + (long)z * sCbBytes;
    const int m0 = blockIdx.y * TM, n0 = blockIdx.x * TN;
    const int tid = threadIdx.x;
    const int w = tid >> 6, lane = tid & 63;
    const int wm = w >> 1, wn = w & 1;
    const int l15 = lane & 15, q = lane >> 4;

    f32x4 acc[4][4] = {};

    // staging geometry: wave w, chunk t (0..3) stages rows [32w+8t, 32w+8t+8).
    // lane i: row = 32w + 8t + (i>>3), LDS slot = i&7 (16B units).
    // source slot = (i&7) ^ (row&7) = (i&7) ^ (i>>3)  (per-lane constant).
    const int srow = 32 * w + (lane >> 3);
    const int skc  = ((lane & 7) ^ (lane >> 3)) * 8;   // pre-swizzled source k offset (elems)
    const ushort_t* Ag = A + (long)(m0 + srow) * lda + skc;
    const ushort_t* Bg = B + (long)(n0 + srow) * ldb + skc;
    ushort_t* aL = aT + (32 * w) * BK;   // wave-uniform LDS bases
    ushort_t* bL = bT + (32 * w) * BK;

    const int sw8 = l15 & 7;   // read-side swizzle key (row&7 == l15&7 for all frags)

    for (int k0 = 0; k0 < K; k0 += BK) {
        __syncthreads();   // previous iter's frag reads done before overwrite
        #pragma unroll
        for (int t = 0; t < 4; t++) {
            gl_lds16(Ag + (long)(8 * t) * lda + k0, aL + (8 * t) * BK);
            gl_lds16(Bg + (long)(8 * t) * ldb + k0, bL + (8 * t) * BK);
        }
        __syncthreads();   // compiler drains vmcnt(0) before s_barrier -> staging visible
        #pragma unroll
        for (int ks = 0; ks < 2; ks++) {
            const int so = ((ks * 4 + q) ^ sw8) * 8;   // swizzled 16B slot -> elem offset
            bf16x8 af[4], bfr[4];
            #pragma unroll
            for (int i = 0; i < 4; i++)
                af[i] = *(bf16x8*)(aT + (wm * 64 + i * 16 + l15) * BK + so);
            #pragma unroll
            for (int j = 0; j < 4; j++)
                bfr[j] = *(bf16x8*)(bT + (wn * 64 + j * 16 + l15) * BK + so);
            #pragma unroll
            for (int i = 0; i < 4; i++)
                #pragma unroll
                for (int j = 0; j < 4; j++)
                    acc[i][j] = __builtin_amdgcn_mfma_f32_16x16x32_bf16(af[i], bfr[j], acc[i][j], 0, 0, 0);
        }
    }

    // epilogue: D lane mapping col = lane&15, row = (lane>>4)*4 + r  (m89-verified)
    #pragma unroll
    for (int i = 0; i < 4; i++) {
        #pragma unroll
        for (int r = 0; r < 4; r++) {
            const int row = m0 + wm * 64 + i * 16 + q * 4 + r;
            #pragma unroll
            for (int j = 0; j < 4; j++) {
                const int col = n0 + wn * 64 + j * 16 + l15;
                float v = acc[i][j][r] * alpha;
                if (epi == 1) v = fmaxf(v, 0.0f);
                else if (epi == 2) v = fmaxf(v, 0.0f) * aux[col];
                else if (epi == 3) v = v + aux[col];
                else if (epi == 4) v = fmaxf(v + aux[col], 0.0f);
                else if (epi == 5) v = v + aux[(long)z * sAuxb + (long)row * ldaux + col];
                if (outF32) ((float*)Cb)[(long)row * ldc + col] = v;
                else        ((ushort_t*)Cb)[(long)row * ldc + col] = f2bf(v);
            }
        }
    }
}

// ---------------- elementwise cast f32 -> bf16 (8 elems/thread) ----------------
__global__ __launch_bounds__(256) void cast_f32_bf16_k(
    const float* __restrict__ in, ushort_t* __restrict__ out, int n8)
{
    const int i = blockIdx.x * 256 + threadIdx.x;
    if (i < n8) {
        float4 a = *(const float4*)(in + (long)i * 8);
        float4 b = *(const float4*)(in + (long)i * 8 + 4);
        us8 o;
        o[0] = f2bf(a.x); o[1] = f2bf(a.y); o[2] = f2bf(a.z); o[3] = f2bf(a.w);
        o[4] = f2bf(b.x); o[5] = f2bf(b.y); o[6] = f2bf(b.z); o[7] = f2bf(b.w);
        *(us8*)(out + (long)i * 8) = o;
    }
}

// ---------------- cast-transpose: out[z][c][r] = bf16(in[z][r][c]), in f32 ----------------
__global__ __launch_bounds__(256) void transpose_f32_bf16(
    const float* __restrict__ in, ushort_t* __restrict__ out,
    int R, int Cn, long sIn, long sOut)
{
    __shared__ ushort_t tile[32][33];
    in += (long)blockIdx.z * sIn;
    out += (long)blockIdx.z * sOut;
    const int c0 = blockIdx.x * 32, r0 = blockIdx.y * 32;
    const int tx = threadIdx.x & 31, ty = threadIdx.x >> 5;   // ty 0..7
    #pragma unroll
    for (int i = 0; i < 4; i++)
        tile[ty + i * 8][tx] = f2bf(in[(long)(r0 + ty + i * 8) * Cn + c0 + tx]);
    __syncthreads();
    #pragma unroll
    for (int i = 0; i < 4; i++)
        out[(long)(c0 + ty + i * 8) * R + r0 + tx] = tile[tx][ty + i * 8];
}

// ---------------- row softmax over S (bf16, in place), f32 masks applied ----------------
__global__ __launch_bounds__(256) void softmax_k(
    ushort_t* __restrict__ S, const float* __restrict__ km, const float* __restrict__ qm)
{
    const long row = blockIdx.x;        // 0..B*T-1 ; b = row>>11
    const int b = (int)(row >> 11);
    ushort_t* Sr = S + row * TT;
    const int tid = threadIdx.x;
    us8 sv = *(us8*)(Sr + tid * 8);
    const float* kmr = km + (long)b * TT + tid * 8;
    float4 k0 = *(const float4*)kmr, k1 = *(const float4*)(kmr + 4);
    float kmv[8] = {k0.x, k0.y, k0.z, k0.w, k1.x, k1.y, k1.z, k1.w};
    float v[8];
    #pragma unroll
    for (int j = 0; j < 8; j++)
        v[j] = (kmv[j] == 0.0f) ? NEG_INF_F : bf2f(sv[j]);
    float mx = v[0];
    #pragma unroll
    for (int j = 1; j < 8; j++) mx = fmaxf(mx, v[j]);
    #pragma unroll
    for (int off = 32; off > 0; off >>= 1) mx = fmaxf(mx, __shfl_xor(mx, off));
    __shared__ float red[8];
    if ((tid & 63) == 0) red[tid >> 6] = mx;
    __syncthreads();
    mx = fmaxf(fmaxf(red[0], red[1]), fmaxf(red[2], red[3]));
    float e[8], s = 0.0f;
    #pragma unroll
    for (int j = 0; j < 8; j++) { e[j] = __expf(v[j] - mx); s += e[j]; }
    #pragma unroll
    for (int off = 32; off > 0; off >>= 1) s += __shfl_xor(s, off);
    if ((tid & 63) == 0) red[4 + (tid >> 6)] = s;
    __syncthreads();
    s = red[4] + red[5] + red[6] + red[7];
    const float scale = qm[row] / s;
    us8 o;
    #pragma unroll
    for (int j = 0; j < 8; j++) o[j] = f2bf(e[j] * scale);
    *(us8*)(Sr + tid * 8) = o;   // same addresses this thread read: no hazard
}

// ---------------- LayerNorm rows of bf16 -> bf16 (f32 gamma/beta) ----------------
__global__ __launch_bounds__(256) void ln_k(
    const ushort_t* __restrict__ olin, ushort_t* __restrict__ outp,
    const float* __restrict__ gamma, const float* __restrict__ beta)
{
    const long row = blockIdx.x;
    const ushort_t* xr = olin + row * CC;
    const int tid = threadIdx.x;
    us4 xq = *(const us4*)(xr + tid * 4);
    float xs[4] = {bf2f(xq[0]), bf2f(xq[1]), bf2f(xq[2]), bf2f(xq[3])};
    float s = xs[0] + xs[1] + xs[2] + xs[3];
    float ss = xs[0]*xs[0] + xs[1]*xs[1] + xs[2]*xs[2] + xs[3]*xs[3];
    #pragma unroll
    for (int off = 32; off > 0; off >>= 1) { s += __shfl_xor(s, off); ss += __shfl_xor(ss, off); }
    __shared__ float red[8];
    if ((tid & 63) == 0) { red[tid >> 6] = s; red[4 + (tid >> 6)] = ss; }
    __syncthreads();
    s = red[0] + red[1] + red[2] + red[3];
    ss = red[4] + red[5] + red[6] + red[7];
    const float mu = s * (1.0f / CC);
    const float var = ss * (1.0f / CC) - mu * mu;
    const float rstd = rsqrtf(var + 1e-6f);
    float4 gv = *(const float4*)(gamma + tid * 4);
    float4 bv = *(const float4*)(beta + tid * 4);
    float gs[4] = {gv.x, gv.y, gv.z, gv.w}, bs[4] = {bv.x, bv.y, bv.z, bv.w};
    us4 o;
    #pragma unroll
    for (int j = 0; j < 4; j++)
        o[j] = f2bf((xs[j] - mu) * rstd * gs[j] + bs[j]);
    *(us4*)(outp + row * CC + tid * 4) = o;
}

extern "C" void kernel_launch(void* const* d_in, const int* in_sizes, int n_in,
                              void* d_out, int out_size, void* d_ws, size_t ws_size,
                              hipStream_t stream)
{
    // ALL inputs/outputs are FLOAT32.
    const float* queries     = (const float*)d_in[0];
    const float* keys        = (const float*)d_in[1];
    const float* key_masks   = (const float*)d_in[2];
    const float* query_masks = (const float*)d_in[3];
    const float* u           = (const float*)d_in[4];
    const float* dd          = (const float*)d_in[5];
    const float* W1          = (const float*)d_in[6];
    const float* b1          = (const float*)d_in[7];
    const float* W2          = (const float*)d_in[8];
    const float* b2          = (const float*)d_in[9];
    const float* g1          = (const float*)d_in[10];
    const float* be1         = (const float*)d_in[11];

    // ws lifetime-packed into 128 MiB. All internal staging is bf16.
    //   f1   @ [0,32)      <- relu(Qbf@uT)*dd          ; then keysT, then W1T/W2T
    //   f2   @ [32,64)     <- relu(Kbf@uT)             ; then olin
    //   uT   @ [64,66)     (dead once S written)
    //   Qbf  @ [66,98)     (dead after f1) -> Kbf same region (dead after f2)
    //   S    @ [64,128)    (dead after AV) -> lnb@64, hb@96
    char* ws = (char*)d_ws;
    const long MiB = 1 << 20;
    ushort_t* f1    = (ushort_t*)(ws + 0 * MiB);
    ushort_t* f2    = (ushort_t*)(ws + 32 * MiB);
    ushort_t* uT    = (ushort_t*)(ws + 64 * MiB);
    ushort_t* Qbf   = (ushort_t*)(ws + 66 * MiB);
    ushort_t* Kbf   = (ushort_t*)(ws + 66 * MiB);
    ushort_t* S     = (ushort_t*)(ws + 64 * MiB);
    ushort_t* keysT = (ushort_t*)(ws + 0 * MiB);    // f1 dead after S-gemm
    ushort_t* olin  = (ushort_t*)(ws + 32 * MiB);   // f2 dead after S-gemm
    ushort_t* W1T   = (ushort_t*)(ws + 0 * MiB);    // keysT dead after AV
    ushort_t* W2T   = (ushort_t*)(ws + 2 * MiB);
    ushort_t* lnb   = (ushort_t*)(ws + 64 * MiB);   // S dead after AV
    ushort_t* hb    = (ushort_t*)(ws + 96 * MiB);
    (void)in_sizes; (void)n_in; (void)out_size; (void)ws_size;

    const int N8 = BB * TT * CC / 8;   // 2 Mi vec8 groups per [B,T,C] tensor

    // output 0: queries passthrough (f32, 64 MiB)
    hipMemcpyAsync(d_out, d_in[0], (size_t)BB * TT * CC * sizeof(float),
                   hipMemcpyDeviceToDevice, stream);

    // uT[d][c] = bf16(u[c][d])
    transpose_f32_bf16<<<dim3(CC / 32, CC / 32, 1), 256, 0, stream>>>(u, uT, CC, CC, 0, 0);

    // Qbf = bf16(queries); f1 = relu(Qbf@u) * d_diag[col]
    cast_f32_bf16_k<<<N8 / 256, 256, 0, stream>>>(queries, Qbf, N8);
    gemm_bt<<<dim3(CC / TN, (BB * TT) / TM, 1), 256, 0, stream>>>(
        Qbf, 0, CC, uT, 0, CC, f1, 0, CC, 0, CC, 1.0f, 2, dd, 0, 0);
    // Kbf = bf16(keys) (Qbf dead); f2 = relu(Kbf@u)
    cast_f32_bf16_k<<<N8 / 256, 256, 0, stream>>>(keys, Kbf, N8);
    gemm_bt<<<dim3(CC / TN, (BB * TT) / TM, 1), 256, 0, stream>>>(
        Kbf, 0, CC, uT, 0, CC, f2, 0, CC, 0, CC, 1.0f, 1, nullptr, 0, 0);
    // S[b] = (f1[b] @ f2[b]^T) / 32   (bf16 out; uT/Kbf dead)
    gemm_bt<<<dim3(TT / TN, TT / TM, BB), 256, 0, stream>>>(
        f1, (long)TT * CC, CC, f2, (long)TT * CC, CC,
        S, (long)TT * TT * 2, TT, 0, CC, 1.0f / 32.0f, 0, nullptr, 0, 0);
    // softmax rows (key mask -> NEG_INF, multiply by query mask), in place -> P
    softmax_k<<<BB * TT, 256, 0, stream>>>(S, key_masks, query_masks);
    // keysT[b][c][t] = bf16(keys[b][t][c])   (into dead f1 region)
    transpose_f32_bf16<<<dim3(CC / 32, TT / 32, BB), 256, 0, stream>>>(
        keys, keysT, TT, CC, (long)TT * CC, (long)CC * TT);
    // olin[b] = P[b] @ keys[b] + queries[b]   (bf16 out into dead f2 region;
    // queries residual added in f32 via epi 5)
    gemm_bt<<<dim3(CC / TN, TT / TM, BB), 256, 0, stream>>>(
        S, (long)TT * TT, TT, keysT, (long)CC * TT, TT,
        olin, (long)TT * CC * 2, CC, 0, TT, 1.0f, 5, queries, (long)TT * CC, CC);
    // W1T/W2T (into dead keysT region)
    transpose_f32_bf16<<<dim3(CC / 32, CC / 32, 1), 256, 0, stream>>>(W1, W1T, CC, CC, 0, 0);
    transpose_f32_bf16<<<dim3(CC / 32, CC / 32, 1), 256, 0, stream>>>(W2, W2T, CC, CC, 0, 0);
    // LayerNorm -> lnb (into dead S region)
    ln_k<<<BB * TT, 256, 0, stream>>>(olin, lnb, g1, be1);
    // h = relu(ln @ W1 + b1)
    gemm_bt<<<dim3(CC / TN, (BB * TT) / TM, 1), 256, 0, stream>>>(
        lnb, 0, CC, W1T, 0, CC, hb, 0, CC, 0, CC, 1.0f, 4, b1, 0, 0);
    // out2 = h @ W2 + b2 -> d_out second half, f32
    gemm_bt<<<dim3(CC / TN, (BB * TT) / TM, 1), 256, 0, stream>>>(
        hb, 0, CC, W2T, 0, CC, (float*)d_out + (long)BB * TT * CC, 0, CC, 1,
        CC, 1.0f, 3, b2, 0, 0);
}

// Round 2
// 744.959 us; speedup vs baseline: 1.2787x; 1.1350x over previous
//
#include <hip/hip_runtime.h>
#include <stdint.h>

typedef unsigned short ushort_t;
typedef __bf16 bf16x8 __attribute__((ext_vector_type(8)));
typedef float f32x4 __attribute__((ext_vector_type(4)));
typedef unsigned short us8 __attribute__((ext_vector_type(8)));
typedef unsigned short us4 __attribute__((ext_vector_type(4)));

#define BB 8
#define TT 2048
#define CC 1024
#define NEG_INF_F (-4294967295.0f)

__device__ __forceinline__ float bf2f(ushort_t u) {
    union { unsigned int i; float f; } v; v.i = ((unsigned int)u) << 16; return v.f;
}
__device__ __forceinline__ ushort_t f2bf(float f) {   // RNE
    union { float f; unsigned int i; } v; v.f = f;
    unsigned int r = (v.i + 0x7fffu + ((v.i >> 16) & 1u)) >> 16;
    return (ushort_t)r;
}

// async global->LDS, 16B per lane. LDS dest = wave-uniform base + lane*16 (m104).
__device__ __forceinline__ void gl_lds16(const ushort_t* g, ushort_t* l)
{
    __builtin_amdgcn_global_load_lds(
        (__attribute__((address_space(1))) void*)(void*)(g),
        (__attribute__((address_space(3))) void*)(l),
        16, 0, 0);
}

// ---------------- MFMA GEMM:  C = epi(alpha * A @ B^T), bf16 inputs ----------------
// A: [M,K] row-major bf16; Bm: [N,K] row-major bf16. C row-major, f32 or bf16.
// Batched via blockIdx.z. epi: 0=none 1=relu 2=relu*aux[col] 3=+aux[col]
// 4=relu(+aux[col]) 5=+aux[z,row,col].
//
// 256x256 8-phase template (T3+T4+T5, m194-m201 lineage), plain HIP:
//  - 8 waves (2M x 4N), 512 thr; per-wave C = 128x64 = acc[8][4] f32x4.
//  - BK=64 per K-tile, split in 2 K-halves of 32. LDS = 2dbuf x {A,B} x 2half
//    x [256 rows][32 k] = 128 KiB. 64B rows -> frag ds_read_b128 naturally
//    conflict-free (bank-quad = (row&1)*4+q, uniform), no swizzle needed.
//  - K-tile = 4 phases: {ds_read 8|4 x b128 ; stage 1 half (2 x gl_lds) ;
//    s_barrier ; lgkmcnt(0)+sched_barrier (rule #18) ; setprio(1) ; 16 MFMA ;
//    setprio(0) ; s_barrier}.
//  - Stage schedule during tile t: [t+1 A-h1, t+1 B-h1, t+2 A-h0, t+2 B-h0];
//    every write targets a region whose readers retired at a prior barrier.
//  - Counted s_waitcnt vmcnt(4) once per tile boundary (queue 12 -> retire 8 =
//    all of tile t+1); tails (tk >= NT-2) drain vmcnt(0). Requires NT >= 2.
#define BM 256
#define BN 256
#define BKT 64
#define HKK 32

__global__ __launch_bounds__(512, 2) void gemm_bt(
    const ushort_t* __restrict__ Am, long sAe, int lda,
    const ushort_t* __restrict__ Bm, long sBe, int ldb,
    void* __restrict__ Cm, long sCbBytes, int ldc, int outF32,
    int K, float alpha, int epi,
    const float* __restrict__ aux, long sAuxb, int ldaux)
{
    __shared__ ushort_t lds[8][256 * HKK];   // [dbuf*4 + mat*2 + khalf] : 128 KiB
    const int z = blockIdx.z;
    const ushort_t* A = Am + (long)z * sAe;
    const ushort_t* B = Bm + (long)z * sBe;
    char* Cb = (char*)Cm + (long)z * sCbBytes;
    const int m0 = blockIdx.y * BM, n0 = blockIdx.x * BN;
    const int tid = threadIdx.x;
    const int w = tid >> 6, lane = tid & 63;
    const int wm = w >> 2, wn = w & 3;          // 2 x 4 wave grid
    const int l15 = lane & 15, q = lane >> 4;

    f32x4 acc[8][4] = {};

    // staging: half-tile = 256 rows x 32 k (16 KiB) = 16 chunks of 16 rows;
    // chunk = j*8 + w. lane i: row = chunk*16 + (i>>2), kslot = i&3; LDS dest
    // is linear chunk_base + i*16B (matches gl_lds wave-uniform+lane*16).
    const int srow = w * 16 + (lane >> 2);
    const int skoff = (lane & 3) * 8;
    const ushort_t* Ag = A + (long)(m0 + srow) * lda + skoff;
    const ushort_t* Bg = B + (long)(n0 + srow) * ldb + skoff;

#define STAGE_A(c, h, tk) do { \
    const ushort_t* _g = Ag + (long)(tk) * BKT + (h) * HKK; \
    ushort_t* _l = &lds[(c) * 4 + (h)][w * 512]; \
    gl_lds16(_g, _l); \
    gl_lds16(_g + (long)128 * lda, _l + 4096); } while (0)
#define STAGE_B(c, h, tk) do { \
    const ushort_t* _g = Bg + (long)(tk) * BKT + (h) * HKK; \
    ushort_t* _l = &lds[(c) * 4 + 2 + (h)][w * 512]; \
    gl_lds16(_g, _l); \
    gl_lds16(_g + (long)128 * ldb, _l + 4096); } while (0)
#define RD_A(c, h, mf) (*(const bf16x8*)&lds[(c) * 4 + (h)][(wm * 128 + (mf) * 16 + l15) * HKK + q * 8])
#define RD_B(c, h, nf) (*(const bf16x8*)&lds[(c) * 4 + 2 + (h)][(wn * 64 + (nf) * 16 + l15) * HKK + q * 8])
#define FENCE() asm volatile("" ::: "memory")
#define BARRIER() do { FENCE(); __builtin_amdgcn_s_barrier(); FENCE(); } while (0)
#define WAIT_LGKM0() do { asm volatile("s_waitcnt lgkmcnt(0)" ::: "memory"); \
                          __builtin_amdgcn_sched_barrier(0); } while (0)
#define MFMA16(mbase) do { \
    __builtin_amdgcn_s_setprio(1); \
    _Pragma("unroll") \
    for (int _i = 0; _i < 4; _i++) \
        _Pragma("unroll") \
        for (int _j = 0; _j < 4; _j++) \
            acc[(mbase) + _i][_j] = __builtin_amdgcn_mfma_f32_16x16x32_bf16( \
                af[_i], bfr[_j], acc[(mbase) + _i][_j], 0, 0, 0); \
    __builtin_amdgcn_s_setprio(0); } while (0)

    const int NT = K >> 6;   // K-tiles (NT >= 2 assumed; K in {1024,2048})

    // prologue: tile0 all 4 halves + tile1 h0 halves (12 loads/wave)
    STAGE_A(0, 0, 0); STAGE_B(0, 0, 0);
    STAGE_A(0, 1, 0); STAGE_B(0, 1, 0);
    STAGE_A(1, 0, 1); STAGE_B(1, 0, 1);
    asm volatile("s_waitcnt vmcnt(4)" ::: "memory");   // tile0 fully landed
    BARRIER();

    bf16x8 af[4], bfr[4];
    for (int tk = 0; tk < NT; ++tk) {
        const int c = tk & 1;
        const int pf1 = (tk + 1 < NT), pf2 = (tk + 2 < NT);

        // phase 0: h0, Mfrags 0-3 (+ B h0); stage (t+1) A-h1 into c^1
        #pragma unroll
        for (int i = 0; i < 4; i++) af[i] = RD_A(c, 0, i);
        #pragma unroll
        for (int j = 0; j < 4; j++) bfr[j] = RD_B(c, 0, j);
        if (pf1) STAGE_A(c ^ 1, 1, tk + 1);
        BARRIER();
        WAIT_LGKM0();
        MFMA16(0);
        BARRIER();

        // phase 1: h0, Mfrags 4-7 (B held in regs); stage (t+1) B-h1
        #pragma unroll
        for (int i = 0; i < 4; i++) af[i] = RD_A(c, 0, 4 + i);
        if (pf1) STAGE_B(c ^ 1, 1, tk + 1);
        BARRIER();
        WAIT_LGKM0();
        MFMA16(4);
        BARRIER();

        // phase 2: h1, Mfrags 0-3 (+ B h1); stage (t+2) A-h0 into c
        // (safe: tile t's h0 reads retired at phase-1 barriers)
        #pragma unroll
        for (int i = 0; i < 4; i++) af[i] = RD_A(c, 1, i);
        #pragma unroll
        for (int j = 0; j < 4; j++) bfr[j] = RD_B(c, 1, j);
        if (pf2) STAGE_A(c, 0, tk + 2);
        BARRIER();
        WAIT_LGKM0();
        MFMA16(0);
        BARRIER();

        // phase 3: h1, Mfrags 4-7; stage (t+2) B-h0; tile-boundary vmcnt
        #pragma unroll
        for (int i = 0; i < 4; i++) af[i] = RD_A(c, 1, 4 + i);
        if (pf2) STAGE_B(c, 0, tk + 2);
        if (tk < NT - 2) asm volatile("s_waitcnt vmcnt(4)" ::: "memory");
        else             asm volatile("s_waitcnt vmcnt(0)" ::: "memory");
        BARRIER();
        WAIT_LGKM0();
        MFMA16(4);
        BARRIER();
    }

    // epilogue: D lane mapping col = lane&15, row = (lane>>4)*4 + r  (m89-verified)
    #pragma unroll
    for (int mf = 0; mf < 8; mf++) {
        #pragma unroll
        for (int r = 0; r < 4; r++) {
            const int row = m0 + wm * 128 + mf * 16 + q * 4 + r;
            #pragma unroll
            for (int nf = 0; nf < 4; nf++) {
                const int col = n0 + wn * 64 + nf * 16 + l15;
                float v = acc[mf][nf][r] * alpha;
                if (epi == 1) v = fmaxf(v, 0.0f);
                else if (epi == 2) v = fmaxf(v, 0.0f) * aux[col];
                else if (epi == 3) v = v + aux[col];
                else if (epi == 4) v = fmaxf(v + aux[col], 0.0f);
                else if (epi == 5) v = v + aux[(long)z * sAuxb + (long)row * ldaux + col];
                if (outF32) ((float*)Cb)[(long)row * ldc + col] = v;
                else        ((ushort_t*)Cb)[(long)row * ldc + col] = f2bf(v);
            }
        }
    }
#undef STAGE_A
#undef STAGE_B
#undef RD_A
#undef RD_B
#undef FENCE
#undef BARRIER
#undef WAIT_LGKM0
#undef MFMA16
}

// ---------------- elementwise cast f32 -> bf16 (8 elems/thread) ----------------
__global__ __launch_bounds__(256) void cast_f32_bf16_k(
    const float* __restrict__ in, ushort_t* __restrict__ out, int n8)
{
    const int i = blockIdx.x * 256 + threadIdx.x;
    if (i < n8) {
        float4 a = *(const float4*)(in + (long)i * 8);
        float4 b = *(const float4*)(in + (long)i * 8 + 4);
        us8 o;
        o[0] = f2bf(a.x); o[1] = f2bf(a.y); o[2] = f2bf(a.z); o[3] = f2bf(a.w);
        o[4] = f2bf(b.x); o[5] = f2bf(b.y); o[6] = f2bf(b.z); o[7] = f2bf(b.w);
        *(us8*)(out + (long)i * 8) = o;
    }
}

// ---------------- cast-transpose: out[z][c][r] = bf16(in[z][r][c]), in f32 ----------------
__global__ __launch_bounds__(256) void transpose_f32_bf16(
    const float* __restrict__ in, ushort_t* __restrict__ out,
    int R, int Cn, long sIn, long sOut)
{
    __shared__ ushort_t tile[32][33];
    in += (long)blockIdx.z * sIn;
    out += (long)blockIdx.z * sOut;
    const int c0 = blockIdx.x * 32, r0 = blockIdx.y * 32;
    const int tx = threadIdx.x & 31, ty = threadIdx.x >> 5;   // ty 0..7
    #pragma unroll
    for (int i = 0; i < 4; i++)
        tile[ty + i * 8][tx] = f2bf(in[(long)(r0 + ty + i * 8) * Cn + c0 + tx]);
    __syncthreads();
    #pragma unroll
    for (int i = 0; i < 4; i++)
        out[(long)(c0 + ty + i * 8) * R + r0 + tx] = tile[tx][ty + i * 8];
}

// ---------------- row softmax over S (bf16, in place), f32 masks applied ----------------
__global__ __launch_bounds__(256) void softmax_k(
    ushort_t* __restrict__ S, const float* __restrict__ km, const float* __restrict__ qm)
{
    const long row = blockIdx.x;        // 0..B*T-1 ; b = row>>11
    const int b = (int)(row >> 11);
    ushort_t* Sr = S + row * TT;
    const int tid = threadIdx.x;
    us8 sv = *(us8*)(Sr + tid * 8);
    const float* kmr = km + (long)b * TT + tid * 8;
    float4 k0 = *(const float4*)kmr, k1 = *(const float4*)(kmr + 4);
    float kmv[8] = {k0.x, k0.y, k0.z, k0.w, k1.x, k1.y, k1.z, k1.w};
    float v[8];
    #pragma unroll
    for (int j = 0; j < 8; j++)
        v[j] = (kmv[j] == 0.0f) ? NEG_INF_F : bf2f(sv[j]);
    float mx = v[0];
    #pragma unroll
    for (int j = 1; j < 8; j++) mx = fmaxf(mx, v[j]);
    #pragma unroll
    for (int off = 32; off > 0; off >>= 1) mx = fmaxf(mx, __shfl_xor(mx, off));
    __shared__ float red[8];
    if ((tid & 63) == 0) red[tid >> 6] = mx;
    __syncthreads();
    mx = fmaxf(fmaxf(red[0], red[1]), fmaxf(red[2], red[3]));
    float e[8], s = 0.0f;
    #pragma unroll
    for (int j = 0; j < 8; j++) { e[j] = __expf(v[j] - mx); s += e[j]; }
    #pragma unroll
    for (int off = 32; off > 0; off >>= 1) s += __shfl_xor(s, off);
    if ((tid & 63) == 0) red[4 + (tid >> 6)] = s;
    __syncthreads();
    s = red[4] + red[5] + red[6] + red[7];
    const float scale = qm[row] / s;
    us8 o;
    #pragma unroll
    for (int j = 0; j < 8; j++) o[j] = f2bf(e[j] * scale);
    *(us8*)(Sr + tid * 8) = o;   // same addresses this thread read: no hazard
}

// ---------------- LayerNorm rows of bf16 -> bf16 (f32 gamma/beta) ----------------
__global__ __launch_bounds__(256) void ln_k(
    const ushort_t* __restrict__ olin, ushort_t* __restrict__ outp,
    const float* __restrict__ gamma, const float* __restrict__ beta)
{
    const long row = blockIdx.x;
    const ushort_t* xr = olin + row * CC;
    const int tid = threadIdx.x;
    us4 xq = *(const us4*)(xr + tid * 4);
    float xs[4] = {bf2f(xq[0]), bf2f(xq[1]), bf2f(xq[2]), bf2f(xq[3])};
    float s = xs[0] + xs[1] + xs[2] + xs[3];
    float ss = xs[0]*xs[0] + xs[1]*xs[1] + xs[2]*xs[2] + xs[3]*xs[3];
    #pragma unroll
    for (int off = 32; off > 0; off >>= 1) { s += __shfl_xor(s, off); ss += __shfl_xor(ss, off); }
    __shared__ float red[8];
    if ((tid & 63) == 0) { red[tid >> 6] = s; red[4 + (tid >> 6)] = ss; }
    __syncthreads();
    s = red[0] + red[1] + red[2] + red[3];
    ss = red[4] + red[5] + red[6] + red[7];
    const float mu = s * (1.0f / CC);
    const float var = ss * (1.0f / CC) - mu * mu;
    const float rstd = rsqrtf(var + 1e-6f);
    float4 gv = *(const float4*)(gamma + tid * 4);
    float4 bv = *(const float4*)(beta + tid * 4);
    float gs[4] = {gv.x, gv.y, gv.z, gv.w}, bs[4] = {bv.x, bv.y, bv.z, bv.w};
    us4 o;
    #pragma unroll
    for (int j = 0; j < 4; j++)
        o[j] = f2bf((xs[j] - mu) * rstd * gs[j] + bs[j]);
    *(us4*)(outp + row * CC + tid * 4) = o;
}

extern "C" void kernel_launch(void* const* d_in, const int* in_sizes, int n_in,
                              void* d_out, int out_size, void* d_ws, size_t ws_size,
                              hipStream_t stream)
{
    // ALL inputs/outputs are FLOAT32.
    const float* queries     = (const float*)d_in[0];
    const float* keys        = (const float*)d_in[1];
    const float* key_masks   = (const float*)d_in[2];
    const float* query_masks = (const float*)d_in[3];
    const float* u           = (const float*)d_in[4];
    const float* dd          = (const float*)d_in[5];
    const float* W1          = (const float*)d_in[6];
    const float* b1          = (const float*)d_in[7];
    const float* W2          = (const float*)d_in[8];
    const float* b2          = (const float*)d_in[9];
    const float* g1          = (const float*)d_in[10];
    const float* be1         = (const float*)d_in[11];

    // ws lifetime-packed into 128 MiB. All internal staging is bf16.
    char* ws = (char*)d_ws;
    const long MiB = 1 << 20;
    ushort_t* f1    = (ushort_t*)(ws + 0 * MiB);
    ushort_t* f2    = (ushort_t*)(ws + 32 * MiB);
    ushort_t* uT    = (ushort_t*)(ws + 64 * MiB);
    ushort_t* Qbf   = (ushort_t*)(ws + 66 * MiB);
    ushort_t* Kbf   = (ushort_t*)(ws + 66 * MiB);
    ushort_t* S     = (ushort_t*)(ws + 64 * MiB);
    ushort_t* keysT = (ushort_t*)(ws + 0 * MiB);    // f1 dead after S-gemm
    ushort_t* olin  = (ushort_t*)(ws + 32 * MiB);   // f2 dead after S-gemm
    ushort_t* W1T   = (ushort_t*)(ws + 0 * MiB);    // keysT dead after AV
    ushort_t* W2T   = (ushort_t*)(ws + 2 * MiB);
    ushort_t* lnb   = (ushort_t*)(ws + 64 * MiB);   // S dead after AV
    ushort_t* hb    = (ushort_t*)(ws + 96 * MiB);
    (void)in_sizes; (void)n_in; (void)out_size; (void)ws_size;

    const int N8 = BB * TT * CC / 8;

    // output 0: queries passthrough (f32, 64 MiB)
    hipMemcpyAsync(d_out, d_in[0], (size_t)BB * TT * CC * sizeof(float),
                   hipMemcpyDeviceToDevice, stream);

    // uT[d][c] = bf16(u[c][d])
    transpose_f32_bf16<<<dim3(CC / 32, CC / 32, 1), 256, 0, stream>>>(u, uT, CC, CC, 0, 0);

    // Qbf = bf16(queries); f1 = relu(Qbf@u) * d_diag[col]
    cast_f32_bf16_k<<<N8 / 256, 256, 0, stream>>>(queries, Qbf, N8);
    gemm_bt<<<dim3(CC / BN, (BB * TT) / BM, 1), 512, 0, stream>>>(
        Qbf, 0, CC, uT, 0, CC, f1, 0, CC, 0, CC, 1.0f, 2, dd, 0, 0);
    // Kbf = bf16(keys) (Qbf dead); f2 = relu(Kbf@u)
    cast_f32_bf16_k<<<N8 / 256, 256, 0, stream>>>(keys, Kbf, N8);
    gemm_bt<<<dim3(CC / BN, (BB * TT) / BM, 1), 512, 0, stream>>>(
        Kbf, 0, CC, uT, 0, CC, f2, 0, CC, 0, CC, 1.0f, 1, nullptr, 0, 0);
    // S[b] = (f1[b] @ f2[b]^T) / 32
    gemm_bt<<<dim3(TT / BN, TT / BM, BB), 512, 0, stream>>>(
        f1, (long)TT * CC, CC, f2, (long)TT * CC, CC,
        S, (long)TT * TT * 2, TT, 0, CC, 1.0f / 32.0f, 0, nullptr, 0, 0);
    // softmax rows (key mask -> NEG_INF, multiply by query mask), in place -> P
    softmax_k<<<BB * TT, 256, 0, stream>>>(S, key_masks, query_masks);
    // keysT[b][c][t] = bf16(keys[b][t][c])   (into dead f1 region)
    transpose_f32_bf16<<<dim3(CC / 32, TT / 32, BB), 256, 0, stream>>>(
        keys, keysT, TT, CC, (long)TT * CC, (long)CC * TT);
    // olin[b] = P[b] @ keys[b] + queries[b]  (residual in f32 via epi 5)
    gemm_bt<<<dim3(CC / BN, TT / BM, BB), 512, 0, stream>>>(
        S, (long)TT * TT, TT, keysT, (long)CC * TT, TT,
        olin, (long)TT * CC * 2, CC, 0, TT, 1.0f, 5, queries, (long)TT * CC, CC);
    // W1T/W2T (into dead keysT region)
    transpose_f32_bf16<<<dim3(CC / 32, CC / 32, 1), 256, 0, stream>>>(W1, W1T, CC, CC, 0, 0);
    transpose_f32_bf16<<<dim3(CC / 32, CC / 32, 1), 256, 0, stream>>>(W2, W2T, CC, CC, 0, 0);
    // LayerNorm -> lnb (into dead S region)
    ln_k<<<BB * TT, 256, 0, stream>>>(olin, lnb, g1, be1);
    // h = relu(ln @ W1 + b1)
    gemm_bt<<<dim3(CC / BN, (BB * TT) / BM, 1), 512, 0, stream>>>(
        lnb, 0, CC, W1T, 0, CC, hb, 0, CC, 0, CC, 1.0f, 4, b1, 0, 0);
    // out2 = h @ W2 + b2 -> d_out second half, f32
    gemm_bt<<<dim3(CC / BN, (BB * TT) / BM, 1), 512, 0, stream>>>(
        hb, 0, CC, W2T, 0, CC, (float*)d_out + (long)BB * TT * CC, 0, CC, 1,
        CC, 1.0f, 3, b2, 0, 0);
}

// Round 3
// 720.157 us; speedup vs baseline: 1.3228x; 1.0344x over previous
//
#include <hip/hip_runtime.h>
#include <stdint.h>

typedef unsigned short ushort_t;
typedef __bf16 bf16x8 __attribute__((ext_vector_type(8)));
typedef float f32x4 __attribute__((ext_vector_type(4)));
typedef unsigned short us8 __attribute__((ext_vector_type(8)));
typedef unsigned short us4 __attribute__((ext_vector_type(4)));

#define BB 8
#define TT 2048
#define CC 1024
#define NEG_INF_F (-4294967295.0f)

__device__ __forceinline__ float bf2f(ushort_t u) {
    union { unsigned int i; float f; } v; v.i = ((unsigned int)u) << 16; return v.f;
}
__device__ __forceinline__ ushort_t f2bf(float f) {   // RNE
    union { float f; unsigned int i; } v; v.f = f;
    unsigned int r = (v.i + 0x7fffu + ((v.i >> 16) & 1u)) >> 16;
    return (ushort_t)r;
}

// async global->LDS, 16B per lane. LDS dest = wave-uniform base + lane*16 (m104).
__device__ __forceinline__ void gl_lds16(const ushort_t* g, ushort_t* l)
{
    __builtin_amdgcn_global_load_lds(
        (__attribute__((address_space(1))) void*)(void*)(g),
        (__attribute__((address_space(3))) void*)(l),
        16, 0, 0);
}

// ---------------- MFMA GEMM:  C = epi(alpha * A @ B^T), bf16 inputs ----------------
// A: [M,K] row-major bf16; Bm: [N,K] row-major bf16. C row-major, f32 or bf16.
// Batched via blockIdx.z. epi: 0=none 1=relu 2=relu*aux[col] 3=+aux[col]
// 4=relu(+aux[col]) 5=+aux[z,row,col].
//
// 256x256 8-phase template (T1+T2+T3+T4+T5), plain HIP:
//  - 8 waves (2M x 4N), 512 thr; per-wave C = 128x64 = acc[8][4] f32x4.
//  - BK=64 per K-tile, split in 2 K-halves of 32. LDS = 2dbuf x {A,B} x 2half
//    x [256 rows][32 k] = 128 KiB.
//  - T2: 16B-slot XOR swizzle, key = (row>>1)&3, applied BOTH sides (rule #21):
//    staging pre-swizzles the GLOBAL source k-slot (gl_lds dest stays linear),
//    frag reads XOR the same key -> each 16-lane quarter covers all 32 banks
//    at 2 lanes/bank (free, m136). Round-2's unswizzled layout was ~8-way
//    (bank = (row&1)*16 + q*4; only row parity entered) -> 6.29e6 conflicts.
//  - T1: bijective chunked XCD swizzle (m204) on flattened block id, bx-fastest
//    decomposition: consecutive blocks on one XCD share the A panel and re-hit
//    B panels (<=4 MiB) in that XCD's L2. Round-2 fetched 242 MB for 64 MiB of
//    inputs (3.8x over-fetch) without this.
//  - K-tile = 4 phases: {ds_read 8|4 x b128 ; stage 1 half (2 x gl_lds) ;
//    s_barrier ; lgkmcnt(0)+sched_barrier (rule #18) ; setprio(1) ; 16 MFMA ;
//    setprio(0) ; s_barrier}.
//  - Stage schedule during tile t: [t+1 A-h1, t+1 B-h1, t+2 A-h0, t+2 B-h0];
//    every write targets a region whose readers retired at a prior barrier.
//  - Counted s_waitcnt vmcnt(4) once per tile boundary; tails drain vmcnt(0).
#define BM 256
#define BN 256
#define BKT 64
#define HKK 32

__global__ __launch_bounds__(512, 2) void gemm_bt(
    const ushort_t* __restrict__ Am, long sAe, int lda,
    const ushort_t* __restrict__ Bm, long sBe, int ldb,
    void* __restrict__ Cm, long sCbBytes, int ldc, int outF32,
    int K, float alpha, int epi,
    const float* __restrict__ aux, long sAuxb, int ldaux)
{
    __shared__ ushort_t lds[8][256 * HKK];   // [dbuf*4 + mat*2 + khalf] : 128 KiB

    // T1: bijective chunked XCD swizzle (m204). HW dispatch round-robins linear
    // block id over 8 XCDs -> lin%8 selects XCD; give each XCD a contiguous
    // chunk of the tile space, bx-fastest within the chunk.
    const int gx = gridDim.x, gxy = gx * gridDim.y;
    const int nwg = gxy * gridDim.z;
    const int lin = blockIdx.x + gx * blockIdx.y + gxy * blockIdx.z;
    const int nq = nwg >> 3, nr = nwg & 7;
    const int xcd = lin & 7, loc = lin >> 3;
    const int swz = (xcd < nr ? xcd * (nq + 1) : nr * (nq + 1) + (xcd - nr) * nq) + loc;
    const int bz = swz / gxy;
    const int rem = swz - bz * gxy;
    const int by = rem / gx;
    const int bx = rem - by * gx;

    const int z = bz;
    const ushort_t* A = Am + (long)z * sAe;
    const ushort_t* B = Bm + (long)z * sBe;
    char* Cb = (char*)Cm + (long)z * sCbBytes;
    const int m0 = by * BM, n0 = bx * BN;
    const int tid = threadIdx.x;
    const int w = tid >> 6, lane = tid & 63;
    const int wm = w >> 2, wn = w & 3;          // 2 x 4 wave grid
    const int l15 = lane & 15, q = lane >> 4;

    f32x4 acc[8][4] = {};

    // staging: half-tile = 256 rows x 32 k (16 KiB) = 16 chunks of 16 rows.
    // lane i: row = chunk*16 + (i>>2); LDS slot = i&3 (linear, gl_lds);
    // GLOBAL slot = (i&3) ^ ((row>>1)&3) = (i&3) ^ ((i>>3)&3)  [T2 pre-swizzle].
    const int srow = w * 16 + (lane >> 2);
    const int skoff = ((lane & 3) ^ ((lane >> 3) & 3)) * 8;
    const ushort_t* Ag = A + (long)(m0 + srow) * lda + skoff;
    const ushort_t* Bg = B + (long)(n0 + srow) * ldb + skoff;
    // T2 read-side key: row = 16*frag + l15 -> (row>>1)&3 == (l15>>1)&3
    const int swk = (l15 >> 1) & 3;

#define STAGE_A(c, h, tk) do { \
    const ushort_t* _g = Ag + (long)(tk) * BKT + (h) * HKK; \
    ushort_t* _l = &lds[(c) * 4 + (h)][w * 512]; \
    gl_lds16(_g, _l); \
    gl_lds16(_g + (long)128 * lda, _l + 4096); } while (0)
#define STAGE_B(c, h, tk) do { \
    const ushort_t* _g = Bg + (long)(tk) * BKT + (h) * HKK; \
    ushort_t* _l = &lds[(c) * 4 + 2 + (h)][w * 512]; \
    gl_lds16(_g, _l); \
    gl_lds16(_g + (long)128 * ldb, _l + 4096); } while (0)
#define RD_A(c, h, mf) (*(const bf16x8*)&lds[(c) * 4 + (h)][(wm * 128 + (mf) * 16 + l15) * HKK + ((q ^ swk) * 8)])
#define RD_B(c, h, nf) (*(const bf16x8*)&lds[(c) * 4 + 2 + (h)][(wn * 64 + (nf) * 16 + l15) * HKK + ((q ^ swk) * 8)])
#define FENCE() asm volatile("" ::: "memory")
#define BARRIER() do { FENCE(); __builtin_amdgcn_s_barrier(); FENCE(); } while (0)
#define WAIT_LGKM0() do { asm volatile("s_waitcnt lgkmcnt(0)" ::: "memory"); \
                          __builtin_amdgcn_sched_barrier(0); } while (0)
#define MFMA16(mbase) do { \
    __builtin_amdgcn_s_setprio(1); \
    _Pragma("unroll") \
    for (int _i = 0; _i < 4; _i++) \
        _Pragma("unroll") \
        for (int _j = 0; _j < 4; _j++) \
            acc[(mbase) + _i][_j] = __builtin_amdgcn_mfma_f32_16x16x32_bf16( \
                af[_i], bfr[_j], acc[(mbase) + _i][_j], 0, 0, 0); \
    __builtin_amdgcn_s_setprio(0); } while (0)

    const int NT = K >> 6;   // K-tiles (NT >= 2 assumed; K in {1024,2048})

    // prologue: tile0 all 4 halves + tile1 h0 halves (12 loads/wave)
    STAGE_A(0, 0, 0); STAGE_B(0, 0, 0);
    STAGE_A(0, 1, 0); STAGE_B(0, 1, 0);
    STAGE_A(1, 0, 1); STAGE_B(1, 0, 1);
    asm volatile("s_waitcnt vmcnt(4)" ::: "memory");   // tile0 fully landed
    BARRIER();

    bf16x8 af[4], bfr[4];
    for (int tk = 0; tk < NT; ++tk) {
        const int c = tk & 1;
        const int pf1 = (tk + 1 < NT), pf2 = (tk + 2 < NT);

        // phase 0: h0, Mfrags 0-3 (+ B h0); stage (t+1) A-h1 into c^1
        #pragma unroll
        for (int i = 0; i < 4; i++) af[i] = RD_A(c, 0, i);
        #pragma unroll
        for (int j = 0; j < 4; j++) bfr[j] = RD_B(c, 0, j);
        if (pf1) STAGE_A(c ^ 1, 1, tk + 1);
        BARRIER();
        WAIT_LGKM0();
        MFMA16(0);
        BARRIER();

        // phase 1: h0, Mfrags 4-7 (B held in regs); stage (t+1) B-h1
        #pragma unroll
        for (int i = 0; i < 4; i++) af[i] = RD_A(c, 0, 4 + i);
        if (pf1) STAGE_B(c ^ 1, 1, tk + 1);
        BARRIER();
        WAIT_LGKM0();
        MFMA16(4);
        BARRIER();

        // phase 2: h1, Mfrags 0-3 (+ B h1); stage (t+2) A-h0 into c
        // (safe: tile t's h0 reads retired at phase-1 barriers)
        #pragma unroll
        for (int i = 0; i < 4; i++) af[i] = RD_A(c, 1, i);
        #pragma unroll
        for (int j = 0; j < 4; j++) bfr[j] = RD_B(c, 1, j);
        if (pf2) STAGE_A(c, 0, tk + 2);
        BARRIER();
        WAIT_LGKM0();
        MFMA16(0);
        BARRIER();

        // phase 3: h1, Mfrags 4-7; stage (t+2) B-h0; tile-boundary vmcnt
        #pragma unroll
        for (int i = 0; i < 4; i++) af[i] = RD_A(c, 1, 4 + i);
        if (pf2) STAGE_B(c, 0, tk + 2);
        if (tk < NT - 2) asm volatile("s_waitcnt vmcnt(4)" ::: "memory");
        else             asm volatile("s_waitcnt vmcnt(0)" ::: "memory");
        BARRIER();
        WAIT_LGKM0();
        MFMA16(4);
        BARRIER();
    }

    // epilogue: D lane mapping col = lane&15, row = (lane>>4)*4 + r  (m89-verified)
    #pragma unroll
    for (int mf = 0; mf < 8; mf++) {
        #pragma unroll
        for (int r = 0; r < 4; r++) {
            const int row = m0 + wm * 128 + mf * 16 + q * 4 + r;
            #pragma unroll
            for (int nf = 0; nf < 4; nf++) {
                const int col = n0 + wn * 64 + nf * 16 + l15;
                float v = acc[mf][nf][r] * alpha;
                if (epi == 1) v = fmaxf(v, 0.0f);
                else if (epi == 2) v = fmaxf(v, 0.0f) * aux[col];
                else if (epi == 3) v = v + aux[col];
                else if (epi == 4) v = fmaxf(v + aux[col], 0.0f);
                else if (epi == 5) v = v + aux[(long)z * sAuxb + (long)row * ldaux + col];
                if (outF32) ((float*)Cb)[(long)row * ldc + col] = v;
                else        ((ushort_t*)Cb)[(long)row * ldc + col] = f2bf(v);
            }
        }
    }
#undef STAGE_A
#undef STAGE_B
#undef RD_A
#undef RD_B
#undef FENCE
#undef BARRIER
#undef WAIT_LGKM0
#undef MFMA16
}

// ---------------- elementwise cast f32 -> bf16 (8 elems/thread) ----------------
__global__ __launch_bounds__(256) void cast_f32_bf16_k(
    const float* __restrict__ in, ushort_t* __restrict__ out, int n8)
{
    const int i = blockIdx.x * 256 + threadIdx.x;
    if (i < n8) {
        float4 a = *(const float4*)(in + (long)i * 8);
        float4 b = *(const float4*)(in + (long)i * 8 + 4);
        us8 o;
        o[0] = f2bf(a.x); o[1] = f2bf(a.y); o[2] = f2bf(a.z); o[3] = f2bf(a.w);
        o[4] = f2bf(b.x); o[5] = f2bf(b.y); o[6] = f2bf(b.z); o[7] = f2bf(b.w);
        *(us8*)(out + (long)i * 8) = o;
    }
}

// ---------------- cast-transpose: out[z][c][r] = bf16(in[z][r][c]), in f32 ----------------
__global__ __launch_bounds__(256) void transpose_f32_bf16(
    const float* __restrict__ in, ushort_t* __restrict__ out,
    int R, int Cn, long sIn, long sOut)
{
    __shared__ ushort_t tile[32][33];
    in += (long)blockIdx.z * sIn;
    out += (long)blockIdx.z * sOut;
    const int c0 = blockIdx.x * 32, r0 = blockIdx.y * 32;
    const int tx = threadIdx.x & 31, ty = threadIdx.x >> 5;   // ty 0..7
    #pragma unroll
    for (int i = 0; i < 4; i++)
        tile[ty + i * 8][tx] = f2bf(in[(long)(r0 + ty + i * 8) * Cn + c0 + tx]);
    __syncthreads();
    #pragma unroll
    for (int i = 0; i < 4; i++)
        out[(long)(c0 + ty + i * 8) * R + r0 + tx] = tile[tx][ty + i * 8];
}

// ---------------- row softmax over S (bf16, in place), f32 masks applied ----------------
__global__ __launch_bounds__(256) void softmax_k(
    ushort_t* __restrict__ S, const float* __restrict__ km, const float* __restrict__ qm)
{
    const long row = blockIdx.x;        // 0..B*T-1 ; b = row>>11
    const int b = (int)(row >> 11);
    ushort_t* Sr = S + row * TT;
    const int tid = threadIdx.x;
    us8 sv = *(us8*)(Sr + tid * 8);
    const float* kmr = km + (long)b * TT + tid * 8;
    float4 k0 = *(const float4*)kmr, k1 = *(const float4*)(kmr + 4);
    float kmv[8] = {k0.x, k0.y, k0.z, k0.w, k1.x, k1.y, k1.z, k1.w};
    float v[8];
    #pragma unroll
    for (int j = 0; j < 8; j++)
        v[j] = (kmv[j] == 0.0f) ? NEG_INF_F : bf2f(sv[j]);
    float mx = v[0];
    #pragma unroll
    for (int j = 1; j < 8; j++) mx = fmaxf(mx, v[j]);
    #pragma unroll
    for (int off = 32; off > 0; off >>= 1) mx = fmaxf(mx, __shfl_xor(mx, off));
    __shared__ float red[8];
    if ((tid & 63) == 0) red[tid >> 6] = mx;
    __syncthreads();
    mx = fmaxf(fmaxf(red[0], red[1]), fmaxf(red[2], red[3]));
    float e[8], s = 0.0f;
    #pragma unroll
    for (int j = 0; j < 8; j++) { e[j] = __expf(v[j] - mx); s += e[j]; }
    #pragma unroll
    for (int off = 32; off > 0; off >>= 1) s += __shfl_xor(s, off);
    if ((tid & 63) == 0) red[4 + (tid >> 6)] = s;
    __syncthreads();
    s = red[4] + red[5] + red[6] + red[7];
    const float scale = qm[row] / s;
    us8 o;
    #pragma unroll
    for (int j = 0; j < 8; j++) o[j] = f2bf(e[j] * scale);
    *(us8*)(Sr + tid * 8) = o;   // same addresses this thread read: no hazard
}

// ---------------- LayerNorm rows of bf16 -> bf16 (f32 gamma/beta) ----------------
__global__ __launch_bounds__(256) void ln_k(
    const ushort_t* __restrict__ olin, ushort_t* __restrict__ outp,
    const float* __restrict__ gamma, const float* __restrict__ beta)
{
    const long row = blockIdx.x;
    const ushort_t* xr = olin + row * CC;
    const int tid = threadIdx.x;
    us4 xq = *(const us4*)(xr + tid * 4);
    float xs[4] = {bf2f(xq[0]), bf2f(xq[1]), bf2f(xq[2]), bf2f(xq[3])};
    float s = xs[0] + xs[1] + xs[2] + xs[3];
    float ss = xs[0]*xs[0] + xs[1]*xs[1] + xs[2]*xs[2] + xs[3]*xs[3];
    #pragma unroll
    for (int off = 32; off > 0; off >>= 1) { s += __shfl_xor(s, off); ss += __shfl_xor(ss, off); }
    __shared__ float red[8];
    if ((tid & 63) == 0) { red[tid >> 6] = s; red[4 + (tid >> 6)] = ss; }
    __syncthreads();
    s = red[0] + red[1] + red[2] + red[3];
    ss = red[4] + red[5] + red[6] + red[7];
    const float mu = s * (1.0f / CC);
    const float var = ss * (1.0f / CC) - mu * mu;
    const float rstd = rsqrtf(var + 1e-6f);
    float4 gv = *(const float4*)(gamma + tid * 4);
    float4 bv = *(const float4*)(beta + tid * 4);
    float gs[4] = {gv.x, gv.y, gv.z, gv.w}, bs[4] = {bv.x, bv.y, bv.z, bv.w};
    us4 o;
    #pragma unroll
    for (int j = 0; j < 4; j++)
        o[j] = f2bf((xs[j] - mu) * rstd * gs[j] + bs[j]);
    *(us4*)(outp + row * CC + tid * 4) = o;
}

extern "C" void kernel_launch(void* const* d_in, const int* in_sizes, int n_in,
                              void* d_out, int out_size, void* d_ws, size_t ws_size,
                              hipStream_t stream)
{
    // ALL inputs/outputs are FLOAT32.
    const float* queries     = (const float*)d_in[0];
    const float* keys        = (const float*)d_in[1];
    const float* key_masks   = (const float*)d_in[2];
    const float* query_masks = (const float*)d_in[3];
    const float* u           = (const float*)d_in[4];
    const float* dd          = (const float*)d_in[5];
    const float* W1          = (const float*)d_in[6];
    const float* b1          = (const float*)d_in[7];
    const float* W2          = (const float*)d_in[8];
    const float* b2          = (const float*)d_in[9];
    const float* g1          = (const float*)d_in[10];
    const float* be1         = (const float*)d_in[11];

    // ws lifetime-packed into 128 MiB. All internal staging is bf16.
    char* ws = (char*)d_ws;
    const long MiB = 1 << 20;
    ushort_t* f1    = (ushort_t*)(ws + 0 * MiB);
    ushort_t* f2    = (ushort_t*)(ws + 32 * MiB);
    ushort_t* uT    = (ushort_t*)(ws + 64 * MiB);
    ushort_t* Qbf   = (ushort_t*)(ws + 66 * MiB);
    ushort_t* Kbf   = (ushort_t*)(ws + 66 * MiB);
    ushort_t* S     = (ushort_t*)(ws + 64 * MiB);
    ushort_t* keysT = (ushort_t*)(ws + 0 * MiB);    // f1 dead after S-gemm
    ushort_t* olin  = (ushort_t*)(ws + 32 * MiB);   // f2 dead after S-gemm
    ushort_t* W1T   = (ushort_t*)(ws + 0 * MiB);    // keysT dead after AV
    ushort_t* W2T   = (ushort_t*)(ws + 2 * MiB);
    ushort_t* lnb   = (ushort_t*)(ws + 64 * MiB);   // S dead after AV
    ushort_t* hb    = (ushort_t*)(ws + 96 * MiB);
    (void)in_sizes; (void)n_in; (void)out_size; (void)ws_size;

    const int N8 = BB * TT * CC / 8;

    // output 0: queries passthrough (f32, 64 MiB)
    hipMemcpyAsync(d_out, d_in[0], (size_t)BB * TT * CC * sizeof(float),
                   hipMemcpyDeviceToDevice, stream);

    // uT[d][c] = bf16(u[c][d])
    transpose_f32_bf16<<<dim3(CC / 32, CC / 32, 1), 256, 0, stream>>>(u, uT, CC, CC, 0, 0);

    // Qbf = bf16(queries); f1 = relu(Qbf@u) * d_diag[col]
    cast_f32_bf16_k<<<N8 / 256, 256, 0, stream>>>(queries, Qbf, N8);
    gemm_bt<<<dim3(CC / BN, (BB * TT) / BM, 1), 512, 0, stream>>>(
        Qbf, 0, CC, uT, 0, CC, f1, 0, CC, 0, CC, 1.0f, 2, dd, 0, 0);
    // Kbf = bf16(keys) (Qbf dead); f2 = relu(Kbf@u)
    cast_f32_bf16_k<<<N8 / 256, 256, 0, stream>>>(keys, Kbf, N8);
    gemm_bt<<<dim3(CC / BN, (BB * TT) / BM, 1), 512, 0, stream>>>(
        Kbf, 0, CC, uT, 0, CC, f2, 0, CC, 0, CC, 1.0f, 1, nullptr, 0, 0);
    // S[b] = (f1[b] @ f2[b]^T) / 32
    gemm_bt<<<dim3(TT / BN, TT / BM, BB), 512, 0, stream>>>(
        f1, (long)TT * CC, CC, f2, (long)TT * CC, CC,
        S, (long)TT * TT * 2, TT, 0, CC, 1.0f / 32.0f, 0, nullptr, 0, 0);
    // softmax rows (key mask -> NEG_INF, multiply by query mask), in place -> P
    softmax_k<<<BB * TT, 256, 0, stream>>>(S, key_masks, query_masks);
    // keysT[b][c][t] = bf16(keys[b][t][c])   (into dead f1 region)
    transpose_f32_bf16<<<dim3(CC / 32, TT / 32, BB), 256, 0, stream>>>(
        keys, keysT, TT, CC, (long)TT * CC, (long)CC * TT);
    // olin[b] = P[b] @ keys[b] + queries[b]  (residual in f32 via epi 5)
    gemm_bt<<<dim3(CC / BN, TT / BM, BB), 512, 0, stream>>>(
        S, (long)TT * TT, TT, keysT, (long)CC * TT, TT,
        olin, (long)TT * CC * 2, CC, 0, TT, 1.0f, 5, queries, (long)TT * CC, CC);
    // W1T/W2T (into dead keysT region)
    transpose_f32_bf16<<<dim3(CC / 32, CC / 32, 1), 256, 0, stream>>>(W1, W1T, CC, CC, 0, 0);
    transpose_f32_bf16<<<dim3(CC / 32, CC / 32, 1), 256, 0, stream>>>(W2, W2T, CC, CC, 0, 0);
    // LayerNorm -> lnb (into dead S region)
    ln_k<<<BB * TT, 256, 0, stream>>>(olin, lnb, g1, be1);
    // h = relu(ln @ W1 + b1)
    gemm_bt<<<dim3(CC / BN, (BB * TT) / BM, 1), 512, 0, stream>>>(
        lnb, 0, CC, W1T, 0, CC, hb, 0, CC, 0, CC, 1.0f, 4, b1, 0, 0);
    // out2 = h @ W2 + b2 -> d_out second half, f32
    gemm_bt<<<dim3(CC / BN, (BB * TT) / BM, 1), 512, 0, stream>>>(
        hb, 0, CC, W2T, 0, CC, (float*)d_out + (long)BB * TT * CC, 0, CC, 1,
        CC, 1.0f, 3, b2, 0, 0);
}

// Round 4
// 702.541 us; speedup vs baseline: 1.3559x; 1.0251x over previous
//
#include <hip/hip_runtime.h>
#include <stdint.h>

typedef unsigned short ushort_t;
typedef __bf16 bf16x8 __attribute__((ext_vector_type(8)));
typedef float f32x4 __attribute__((ext_vector_type(4)));
typedef unsigned short us8 __attribute__((ext_vector_type(8)));
typedef unsigned short us4 __attribute__((ext_vector_type(4)));

#define BB 8
#define TT 2048
#define CC 1024
#define NEG_INF_F (-4294967295.0f)

__device__ __forceinline__ float bf2f(ushort_t u) {
    union { unsigned int i; float f; } v; v.i = ((unsigned int)u) << 16; return v.f;
}
__device__ __forceinline__ ushort_t f2bf(float f) {   // RNE
    union { float f; unsigned int i; } v; v.f = f;
    unsigned int r = (v.i + 0x7fffu + ((v.i >> 16) & 1u)) >> 16;
    return (ushort_t)r;
}

// async global->LDS, 16B per lane. LDS dest = wave-uniform base + lane*16 (m104).
__device__ __forceinline__ void gl_lds16(const ushort_t* g, ushort_t* l)
{
    __builtin_amdgcn_global_load_lds(
        (__attribute__((address_space(1))) void*)(void*)(g),
        (__attribute__((address_space(3))) void*)(l),
        16, 0, 0);
}

// ---------------- MFMA GEMM:  C = epi(alpha * A @ B^T), bf16 inputs ----------------
// A: [M,K] row-major bf16; Bm: [N,K] row-major bf16. C row-major, f32 or bf16.
// Batched via blockIdx.z. epi: 0=none 1=relu 2=relu*aux[col] 3=+aux[col]
// 4=relu(+aux[col]) 5=+aux[z,row,col].
//
// 256x256 8-phase template (T2+T3+T4+T5 [+T1 optional]), plain HIP:
//  - 8 waves (2M x 4N), 512 thr; per-wave C = 128x64 = acc[8][4] f32x4.
//  - BK=64 per K-tile, split in 2 K-halves of 32. LDS = 2dbuf x {A,B} x 2half
//    x [256 rows][32 k] = 128 KiB.
//  - T2: 16B-slot XOR swizzle, key = (row>>1)&3, BOTH sides (rule #21):
//    staging pre-swizzles the GLOBAL source k-slot (gl_lds dest stays linear),
//    frag reads XOR the same key -> conflict-free (verified: counter 0, r3).
//  - T1 (swzMode=1): bijective chunked XCD swizzle (m204), bx-fastest. FETCH
//    242->82 MB on batched (r3). swzMode=0 = linear HW order: used for the AV
//    gemm, which REGRESSED 119->151 us under chunking (r3: chunk x epilogue-
//    residual interaction; residual now removed AND mode 0 to be safe).
//  - K-tile = 4 phases: {ds_read 8|4 x b128 ; stage 1 half (2 x gl_lds) ;
//    s_barrier ; lgkmcnt(0)+sched_barrier (rule #18) ; setprio(1) ; 16 MFMA ;
//    setprio(0) ; s_barrier}.
//  - Stage schedule during tile t: [t+1 A-h1, t+1 B-h1, t+2 A-h0, t+2 B-h0];
//    every write targets a region whose readers retired at a prior barrier.
//  - Counted s_waitcnt vmcnt(4) once per tile boundary; tails drain vmcnt(0).
#define BM 256
#define BN 256
#define BKT 64
#define HKK 32

__global__ __launch_bounds__(512, 2) void gemm_bt(
    const ushort_t* __restrict__ Am, long sAe, int lda,
    const ushort_t* __restrict__ Bm, long sBe, int ldb,
    void* __restrict__ Cm, long sCbBytes, int ldc, int outF32,
    int K, float alpha, int epi,
    const float* __restrict__ aux, long sAuxb, int ldaux, int swzMode)
{
    __shared__ ushort_t lds[8][256 * HKK];   // [dbuf*4 + mat*2 + khalf] : 128 KiB

    int bx, by, bz;
    if (swzMode) {
        // T1: bijective chunked XCD swizzle (m204); lin%8 = XCD under HW
        // round-robin dispatch; each XCD gets a contiguous chunk, bx-fastest.
        const int gx = gridDim.x, gxy = gx * gridDim.y;
        const int nwg = gxy * gridDim.z;
        const int lin = blockIdx.x + gx * blockIdx.y + gxy * blockIdx.z;
        const int nq = nwg >> 3, nr = nwg & 7;
        const int xcd = lin & 7, loc = lin >> 3;
        const int swz = (xcd < nr ? xcd * (nq + 1) : nr * (nq + 1) + (xcd - nr) * nq) + loc;
        bz = swz / gxy;
        const int rem = swz - bz * gxy;
        by = rem / gx;
        bx = rem - by * gx;
    } else {
        bx = blockIdx.x; by = blockIdx.y; bz = blockIdx.z;
    }

    const int z = bz;
    const ushort_t* A = Am + (long)z * sAe;
    const ushort_t* B = Bm + (long)z * sBe;
    char* Cb = (char*)Cm + (long)z * sCbBytes;
    const int m0 = by * BM, n0 = bx * BN;
    const int tid = threadIdx.x;
    const int w = tid >> 6, lane = tid & 63;
    const int wm = w >> 2, wn = w & 3;          // 2 x 4 wave grid
    const int l15 = lane & 15, q = lane >> 4;

    f32x4 acc[8][4] = {};

    // staging: half-tile = 256 rows x 32 k (16 KiB) = 16 chunks of 16 rows.
    // lane i: row = chunk*16 + (i>>2); LDS slot = i&3 (linear, gl_lds);
    // GLOBAL slot = (i&3) ^ ((row>>1)&3) = (i&3) ^ ((i>>3)&3)  [T2 pre-swizzle].
    const int srow = w * 16 + (lane >> 2);
    const int skoff = ((lane & 3) ^ ((lane >> 3) & 3)) * 8;
    const ushort_t* Ag = A + (long)(m0 + srow) * lda + skoff;
    const ushort_t* Bg = B + (long)(n0 + srow) * ldb + skoff;
    // T2 read-side key: row = 16*frag + l15 -> (row>>1)&3 == (l15>>1)&3
    const int swk = (l15 >> 1) & 3;

#define STAGE_A(c, h, tk) do { \
    const ushort_t* _g = Ag + (long)(tk) * BKT + (h) * HKK; \
    ushort_t* _l = &lds[(c) * 4 + (h)][w * 512]; \
    gl_lds16(_g, _l); \
    gl_lds16(_g + (long)128 * lda, _l + 4096); } while (0)
#define STAGE_B(c, h, tk) do { \
    const ushort_t* _g = Bg + (long)(tk) * BKT + (h) * HKK; \
    ushort_t* _l = &lds[(c) * 4 + 2 + (h)][w * 512]; \
    gl_lds16(_g, _l); \
    gl_lds16(_g + (long)128 * ldb, _l + 4096); } while (0)
#define RD_A(c, h, mf) (*(const bf16x8*)&lds[(c) * 4 + (h)][(wm * 128 + (mf) * 16 + l15) * HKK + ((q ^ swk) * 8)])
#define RD_B(c, h, nf) (*(const bf16x8*)&lds[(c) * 4 + 2 + (h)][(wn * 64 + (nf) * 16 + l15) * HKK + ((q ^ swk) * 8)])
#define FENCE() asm volatile("" ::: "memory")
#define BARRIER() do { FENCE(); __builtin_amdgcn_s_barrier(); FENCE(); } while (0)
#define WAIT_LGKM0() do { asm volatile("s_waitcnt lgkmcnt(0)" ::: "memory"); \
                          __builtin_amdgcn_sched_barrier(0); } while (0)
#define MFMA16(mbase) do { \
    __builtin_amdgcn_s_setprio(1); \
    _Pragma("unroll") \
    for (int _i = 0; _i < 4; _i++) \
        _Pragma("unroll") \
        for (int _j = 0; _j < 4; _j++) \
            acc[(mbase) + _i][_j] = __builtin_amdgcn_mfma_f32_16x16x32_bf16( \
                af[_i], bfr[_j], acc[(mbase) + _i][_j], 0, 0, 0); \
    __builtin_amdgcn_s_setprio(0); } while (0)

    const int NT = K >> 6;   // K-tiles (NT >= 2 assumed; K in {1024,2048})

    // prologue: tile0 all 4 halves + tile1 h0 halves (12 loads/wave)
    STAGE_A(0, 0, 0); STAGE_B(0, 0, 0);
    STAGE_A(0, 1, 0); STAGE_B(0, 1, 0);
    STAGE_A(1, 0, 1); STAGE_B(1, 0, 1);
    asm volatile("s_waitcnt vmcnt(4)" ::: "memory");   // tile0 fully landed
    BARRIER();

    bf16x8 af[4], bfr[4];
    for (int tk = 0; tk < NT; ++tk) {
        const int c = tk & 1;
        const int pf1 = (tk + 1 < NT), pf2 = (tk + 2 < NT);

        // phase 0: h0, Mfrags 0-3 (+ B h0); stage (t+1) A-h1 into c^1
        #pragma unroll
        for (int i = 0; i < 4; i++) af[i] = RD_A(c, 0, i);
        #pragma unroll
        for (int j = 0; j < 4; j++) bfr[j] = RD_B(c, 0, j);
        if (pf1) STAGE_A(c ^ 1, 1, tk + 1);
        BARRIER();
        WAIT_LGKM0();
        MFMA16(0);
        BARRIER();

        // phase 1: h0, Mfrags 4-7 (B held in regs); stage (t+1) B-h1
        #pragma unroll
        for (int i = 0; i < 4; i++) af[i] = RD_A(c, 0, 4 + i);
        if (pf1) STAGE_B(c ^ 1, 1, tk + 1);
        BARRIER();
        WAIT_LGKM0();
        MFMA16(4);
        BARRIER();

        // phase 2: h1, Mfrags 0-3 (+ B h1); stage (t+2) A-h0 into c
        // (safe: tile t's h0 reads retired at phase-1 barriers)
        #pragma unroll
        for (int i = 0; i < 4; i++) af[i] = RD_A(c, 1, i);
        #pragma unroll
        for (int j = 0; j < 4; j++) bfr[j] = RD_B(c, 1, j);
        if (pf2) STAGE_A(c, 0, tk + 2);
        BARRIER();
        WAIT_LGKM0();
        MFMA16(0);
        BARRIER();

        // phase 3: h1, Mfrags 4-7; stage (t+2) B-h0; tile-boundary vmcnt
        #pragma unroll
        for (int i = 0; i < 4; i++) af[i] = RD_A(c, 1, 4 + i);
        if (pf2) STAGE_B(c, 0, tk + 2);
        if (tk < NT - 2) asm volatile("s_waitcnt vmcnt(4)" ::: "memory");
        else             asm volatile("s_waitcnt vmcnt(0)" ::: "memory");
        BARRIER();
        WAIT_LGKM0();
        MFMA16(4);
        BARRIER();
    }

    // epilogue: D lane mapping col = lane&15, row = (lane>>4)*4 + r  (m89-verified)
    #pragma unroll
    for (int mf = 0; mf < 8; mf++) {
        #pragma unroll
        for (int r = 0; r < 4; r++) {
            const int row = m0 + wm * 128 + mf * 16 + q * 4 + r;
            #pragma unroll
            for (int nf = 0; nf < 4; nf++) {
                const int col = n0 + wn * 64 + nf * 16 + l15;
                float v = acc[mf][nf][r] * alpha;
                if (epi == 1) v = fmaxf(v, 0.0f);
                else if (epi == 2) v = fmaxf(v, 0.0f) * aux[col];
                else if (epi == 3) v = v + aux[col];
                else if (epi == 4) v = fmaxf(v + aux[col], 0.0f);
                else if (epi == 5) v = v + aux[(long)z * sAuxb + (long)row * ldaux + col];
                if (outF32) ((float*)Cb)[(long)row * ldc + col] = v;
                else        ((ushort_t*)Cb)[(long)row * ldc + col] = f2bf(v);
            }
        }
    }
#undef STAGE_A
#undef STAGE_B
#undef RD_A
#undef RD_B
#undef FENCE
#undef BARRIER
#undef WAIT_LGKM0
#undef MFMA16
}

// ---------------- elementwise cast f32 -> bf16 (8 elems/thread) ----------------
__global__ __launch_bounds__(256) void cast_f32_bf16_k(
    const float* __restrict__ in, ushort_t* __restrict__ out, int n8)
{
    const int i = blockIdx.x * 256 + threadIdx.x;
    if (i < n8) {
        float4 a = *(const float4*)(in + (long)i * 8);
        float4 b = *(const float4*)(in + (long)i * 8 + 4);
        us8 o;
        o[0] = f2bf(a.x); o[1] = f2bf(a.y); o[2] = f2bf(a.z); o[3] = f2bf(a.w);
        o[4] = f2bf(b.x); o[5] = f2bf(b.y); o[6] = f2bf(b.z); o[7] = f2bf(b.w);
        *(us8*)(out + (long)i * 8) = o;
    }
}

// ---------------- cast-transpose: out[z][c][r] = bf16(in[z][r][c]), in f32 ----------------
__global__ __launch_bounds__(256) void transpose_f32_bf16(
    const float* __restrict__ in, ushort_t* __restrict__ out,
    int R, int Cn, long sIn, long sOut)
{
    __shared__ ushort_t tile[32][33];
    in += (long)blockIdx.z * sIn;
    out += (long)blockIdx.z * sOut;
    const int c0 = blockIdx.x * 32, r0 = blockIdx.y * 32;
    const int tx = threadIdx.x & 31, ty = threadIdx.x >> 5;   // ty 0..7
    #pragma unroll
    for (int i = 0; i < 4; i++)
        tile[ty + i * 8][tx] = f2bf(in[(long)(r0 + ty + i * 8) * Cn + c0 + tx]);
    __syncthreads();
    #pragma unroll
    for (int i = 0; i < 4; i++)
        out[(long)(c0 + ty + i * 8) * R + r0 + tx] = tile[tx][ty + i * 8];
}

// ---------------- row softmax over S (bf16, in place), f32 masks applied ----------------
__global__ __launch_bounds__(256) void softmax_k(
    ushort_t* __restrict__ S, const float* __restrict__ km, const float* __restrict__ qm)
{
    const long row = blockIdx.x;        // 0..B*T-1 ; b = row>>11
    const int b = (int)(row >> 11);
    ushort_t* Sr = S + row * TT;
    const int tid = threadIdx.x;
    us8 sv = *(us8*)(Sr + tid * 8);
    const float* kmr = km + (long)b * TT + tid * 8;
    float4 k0 = *(const float4*)kmr, k1 = *(const float4*)(kmr + 4);
    float kmv[8] = {k0.x, k0.y, k0.z, k0.w, k1.x, k1.y, k1.z, k1.w};
    float v[8];
    #pragma unroll
    for (int j = 0; j < 8; j++)
        v[j] = (kmv[j] == 0.0f) ? NEG_INF_F : bf2f(sv[j]);
    float mx = v[0];
    #pragma unroll
    for (int j = 1; j < 8; j++) mx = fmaxf(mx, v[j]);
    #pragma unroll
    for (int off = 32; off > 0; off >>= 1) mx = fmaxf(mx, __shfl_xor(mx, off));
    __shared__ float red[8];
    if ((tid & 63) == 0) red[tid >> 6] = mx;
    __syncthreads();
    mx = fmaxf(fmaxf(red[0], red[1]), fmaxf(red[2], red[3]));
    float e[8], s = 0.0f;
    #pragma unroll
    for (int j = 0; j < 8; j++) { e[j] = __expf(v[j] - mx); s += e[j]; }
    #pragma unroll
    for (int off = 32; off > 0; off >>= 1) s += __shfl_xor(s, off);
    if ((tid & 63) == 0) red[4 + (tid >> 6)] = s;
    __syncthreads();
    s = red[4] + red[5] + red[6] + red[7];
    const float scale = qm[row] / s;
    us8 o;
    #pragma unroll
    for (int j = 0; j < 8; j++) o[j] = f2bf(e[j] * scale);
    *(us8*)(Sr + tid * 8) = o;   // same addresses this thread read: no hazard
}

// ---------------- LayerNorm rows of (olin_bf16 + resid_f32) -> bf16 ----------------
// residual fused here (round-4): removes the 64 MiB f32 aux read from the AV
// gemm's epilogue (r3: that read regressed AV 119->151 us under XCD chunking).
__global__ __launch_bounds__(256) void ln_res_k(
    const ushort_t* __restrict__ olin, const float* __restrict__ resid,
    ushort_t* __restrict__ outp,
    const float* __restrict__ gamma, const float* __restrict__ beta)
{
    const long row = blockIdx.x;
    const ushort_t* xr = olin + row * CC;
    const float* rr = resid + row * CC;
    const int tid = threadIdx.x;
    us4 xq = *(const us4*)(xr + tid * 4);
    float4 rv = *(const float4*)(rr + tid * 4);
    float xs[4] = {bf2f(xq[0]) + rv.x, bf2f(xq[1]) + rv.y,
                   bf2f(xq[2]) + rv.z, bf2f(xq[3]) + rv.w};
    float s = xs[0] + xs[1] + xs[2] + xs[3];
    float ss = xs[0]*xs[0] + xs[1]*xs[1] + xs[2]*xs[2] + xs[3]*xs[3];
    #pragma unroll
    for (int off = 32; off > 0; off >>= 1) { s += __shfl_xor(s, off); ss += __shfl_xor(ss, off); }
    __shared__ float red[8];
    if ((tid & 63) == 0) { red[tid >> 6] = s; red[4 + (tid >> 6)] = ss; }
    __syncthreads();
    s = red[0] + red[1] + red[2] + red[3];
    ss = red[4] + red[5] + red[6] + red[7];
    const float mu = s * (1.0f / CC);
    const float var = ss * (1.0f / CC) - mu * mu;
    const float rstd = rsqrtf(var + 1e-6f);
    float4 gv = *(const float4*)(gamma + tid * 4);
    float4 bv = *(const float4*)(beta + tid * 4);
    float gs[4] = {gv.x, gv.y, gv.z, gv.w}, bs[4] = {bv.x, bv.y, bv.z, bv.w};
    us4 o;
    #pragma unroll
    for (int j = 0; j < 4; j++)
        o[j] = f2bf((xs[j] - mu) * rstd * gs[j] + bs[j]);
    *(us4*)(outp + row * CC + tid * 4) = o;
}

extern "C" void kernel_launch(void* const* d_in, const int* in_sizes, int n_in,
                              void* d_out, int out_size, void* d_ws, size_t ws_size,
                              hipStream_t stream)
{
    // ALL inputs/outputs are FLOAT32.
    const float* queries     = (const float*)d_in[0];
    const float* keys        = (const float*)d_in[1];
    const float* key_masks   = (const float*)d_in[2];
    const float* query_masks = (const float*)d_in[3];
    const float* u           = (const float*)d_in[4];
    const float* dd          = (const float*)d_in[5];
    const float* W1          = (const float*)d_in[6];
    const float* b1          = (const float*)d_in[7];
    const float* W2          = (const float*)d_in[8];
    const float* b2          = (const float*)d_in[9];
    const float* g1          = (const float*)d_in[10];
    const float* be1         = (const float*)d_in[11];

    // ws lifetime-packed into 128 MiB. All internal staging is bf16.
    char* ws = (char*)d_ws;
    const long MiB = 1 << 20;
    ushort_t* f1    = (ushort_t*)(ws + 0 * MiB);
    ushort_t* f2    = (ushort_t*)(ws + 32 * MiB);
    ushort_t* uT    = (ushort_t*)(ws + 64 * MiB);
    ushort_t* Qbf   = (ushort_t*)(ws + 66 * MiB);
    ushort_t* Kbf   = (ushort_t*)(ws + 66 * MiB);
    ushort_t* S     = (ushort_t*)(ws + 64 * MiB);
    ushort_t* keysT = (ushort_t*)(ws + 0 * MiB);    // f1 dead after S-gemm
    ushort_t* olin  = (ushort_t*)(ws + 32 * MiB);   // f2 dead after S-gemm
    ushort_t* W1T   = (ushort_t*)(ws + 0 * MiB);    // keysT dead after AV
    ushort_t* W2T   = (ushort_t*)(ws + 2 * MiB);
    ushort_t* lnb   = (ushort_t*)(ws + 64 * MiB);   // S dead after AV
    ushort_t* hb    = (ushort_t*)(ws + 96 * MiB);
    (void)in_sizes; (void)n_in; (void)out_size; (void)ws_size;

    const int N8 = BB * TT * CC / 8;

    // output 0: queries passthrough (f32, 64 MiB)
    hipMemcpyAsync(d_out, d_in[0], (size_t)BB * TT * CC * sizeof(float),
                   hipMemcpyDeviceToDevice, stream);

    // uT[d][c] = bf16(u[c][d])
    transpose_f32_bf16<<<dim3(CC / 32, CC / 32, 1), 256, 0, stream>>>(u, uT, CC, CC, 0, 0);

    // Qbf = bf16(queries); f1 = relu(Qbf@u) * d_diag[col]
    cast_f32_bf16_k<<<N8 / 256, 256, 0, stream>>>(queries, Qbf, N8);
    gemm_bt<<<dim3(CC / BN, (BB * TT) / BM, 1), 512, 0, stream>>>(
        Qbf, 0, CC, uT, 0, CC, f1, 0, CC, 0, CC, 1.0f, 2, dd, 0, 0, 1);
    // Kbf = bf16(keys) (Qbf dead); f2 = relu(Kbf@u)
    cast_f32_bf16_k<<<N8 / 256, 256, 0, stream>>>(keys, Kbf, N8);
    gemm_bt<<<dim3(CC / BN, (BB * TT) / BM, 1), 512, 0, stream>>>(
        Kbf, 0, CC, uT, 0, CC, f2, 0, CC, 0, CC, 1.0f, 1, nullptr, 0, 0, 1);
    // S[b] = (f1[b] @ f2[b]^T) / 32   (chunked mode: k-window streams from L2)
    gemm_bt<<<dim3(TT / BN, TT / BM, BB), 512, 0, stream>>>(
        f1, (long)TT * CC, CC, f2, (long)TT * CC, CC,
        S, (long)TT * TT * 2, TT, 0, CC, 1.0f / 32.0f, 0, nullptr, 0, 0, 1);
    // softmax rows (key mask -> NEG_INF, multiply by query mask), in place -> P
    softmax_k<<<BB * TT, 256, 0, stream>>>(S, key_masks, query_masks);
    // keysT[b][c][t] = bf16(keys[b][t][c])   (into dead f1 region)
    transpose_f32_bf16<<<dim3(CC / 32, TT / 32, BB), 256, 0, stream>>>(
        keys, keysT, TT, CC, (long)TT * CC, (long)CC * TT);
    // olin[b] = P[b] @ keys[b]   (NO residual here; linear dispatch mode 0 —
    // this launch regressed under chunking in r3)
    gemm_bt<<<dim3(CC / BN, TT / BM, BB), 512, 0, stream>>>(
        S, (long)TT * TT, TT, keysT, (long)CC * TT, TT,
        olin, (long)TT * CC * 2, CC, 0, TT, 1.0f, 0, nullptr, 0, 0, 0);
    // W1T/W2T (into dead keysT region)
    transpose_f32_bf16<<<dim3(CC / 32, CC / 32, 1), 256, 0, stream>>>(W1, W1T, CC, CC, 0, 0);
    transpose_f32_bf16<<<dim3(CC / 32, CC / 32, 1), 256, 0, stream>>>(W2, W2T, CC, CC, 0, 0);
    // LayerNorm(olin + queries) -> lnb (residual fused; into dead S region)
    ln_res_k<<<BB * TT, 256, 0, stream>>>(olin, queries, lnb, g1, be1);
    // h = relu(ln @ W1 + b1)
    gemm_bt<<<dim3(CC / BN, (BB * TT) / BM, 1), 512, 0, stream>>>(
        lnb, 0, CC, W1T, 0, CC, hb, 0, CC, 0, CC, 1.0f, 4, b1, 0, 0, 1);
    // out2 = h @ W2 + b2 -> d_out second half, f32
    gemm_bt<<<dim3(CC / BN, (BB * TT) / BM, 1), 512, 0, stream>>>(
        hb, 0, CC, W2T, 0, CC, (float*)d_out + (long)BB * TT * CC, 0, CC, 1,
        CC, 1.0f, 3, b2, 0, 0, 1);
}

// Round 5
// 699.906 us; speedup vs baseline: 1.3610x; 1.0038x over previous
//
#include <hip/hip_runtime.h>
#include <stdint.h>

typedef unsigned short ushort_t;
typedef __bf16 bf16x8 __attribute__((ext_vector_type(8)));
typedef float f32x4 __attribute__((ext_vector_type(4)));
typedef unsigned short us8 __attribute__((ext_vector_type(8)));
typedef unsigned short us4 __attribute__((ext_vector_type(4)));

#define BB 8
#define TT 2048
#define CC 1024
#define NEG_INF_F (-4294967295.0f)

__device__ __forceinline__ float bf2f(ushort_t u) {
    union { unsigned int i; float f; } v; v.i = ((unsigned int)u) << 16; return v.f;
}
__device__ __forceinline__ ushort_t f2bf(float f) {   // RNE
    union { float f; unsigned int i; } v; v.f = f;
    unsigned int r = (v.i + 0x7fffu + ((v.i >> 16) & 1u)) >> 16;
    return (ushort_t)r;
}

// async global->LDS, 16B per lane. LDS dest = wave-uniform base + lane*16 (m104).
__device__ __forceinline__ void gl_lds16(const ushort_t* g, ushort_t* l)
{
    __builtin_amdgcn_global_load_lds(
        (__attribute__((address_space(1))) void*)(void*)(g),
        (__attribute__((address_space(3))) void*)(l),
        16, 0, 0);
}

// ---------------- MFMA GEMM:  C = epi(alpha * A @ B^T), bf16 inputs ----------------
// A: [M,K] row-major bf16; Bm: [N,K] row-major bf16. C row-major, f32 or bf16.
// Batched via blockIdx.z. epi: 0=none 1=relu 2=relu*aux[col] 3=+aux[col]
// 4=relu(+aux[col]) 5=+aux[z,row,col].
//
// 256x256 template (T1 optional + T2 + counted-vmcnt pipeline + setprio):
//  - 8 waves (2M x 4N), 512 thr; per-wave C = 128x64 = acc[8][4] f32x4.
//  - BK=64 per K-tile, 2 k-halves of 32. LDS = 2dbuf x {A,B} x 2half
//    x [256 rows][32 k] = 128 KiB (1 block/CU -> VGPR up to 256 is free).
//  - r5 restructure: 2 phases per K-tile (was 4), 32-MFMA clusters with
//    af[8] x bfr[4]. NO explicit lgkmcnt(0): frag reads are plain loads, so
//    the compiler emits fine-grained descending lgkmcnt per consuming MFMA
//    (m97) -> read-drain overlaps MFMA. r4's forced full drain serialized
//    [LDS drain][MFMA] every phase -> 1762 cyc/phase vs 621 floor.
//  - sched_barrier(0) AFTER each MFMA cluster: register-only MFMAs can sink
//    past asm memory clobbers (rule #18); pinning them before the end barrier
//    preserves the "reads serviced before buffer overwrite" invariant.
//  - T2: 16B-slot XOR swizzle, key (row>>1)&3, BOTH sides (rule #21); source
//    pre-swizzled so gl_lds dest stays linear. Conflicts = 0 (r3/r4 verified).
//  - Stage schedule: tile t phase 0 stages (t+1,h1) into c^1; phase 1 stages
//    (t+2,h0) into c. Reads of a region are always fully serviced (consumed
//    by MFMAs before the phase-end barrier) before the overwriting gl_lds is
//    issued. vmcnt(4) at tile boundary retires (t+1,h0)+(t+1,h1), leaving
//    (t+2,h0) in flight; tails drain vmcnt(0). NT >= 2 required.
#define BM 256
#define BN 256
#define BKT 64
#define HKK 32

__global__ __launch_bounds__(512, 2) void gemm_bt(
    const ushort_t* __restrict__ Am, long sAe, int lda,
    const ushort_t* __restrict__ Bm, long sBe, int ldb,
    void* __restrict__ Cm, long sCbBytes, int ldc, int outF32,
    int K, float alpha, int epi,
    const float* __restrict__ aux, long sAuxb, int ldaux, int swzMode)
{
    __shared__ ushort_t lds[8][256 * HKK];   // [dbuf*4 + mat*2 + khalf] : 128 KiB

    int bx, by, bz;
    if (swzMode) {
        // T1: bijective chunked XCD swizzle (m204); lin%8 = XCD under HW
        // round-robin dispatch; each XCD gets a contiguous chunk, bx-fastest.
        const int gx = gridDim.x, gxy = gx * gridDim.y;
        const int nwg = gxy * gridDim.z;
        const int lin = blockIdx.x + gx * blockIdx.y + gxy * blockIdx.z;
        const int nq = nwg >> 3, nr = nwg & 7;
        const int xcd = lin & 7, loc = lin >> 3;
        const int swz = (xcd < nr ? xcd * (nq + 1) : nr * (nq + 1) + (xcd - nr) * nq) + loc;
        bz = swz / gxy;
        const int rem = swz - bz * gxy;
        by = rem / gx;
        bx = rem - by * gx;
    } else {
        bx = blockIdx.x; by = blockIdx.y; bz = blockIdx.z;
    }

    const int z = bz;
    const ushort_t* A = Am + (long)z * sAe;
    const ushort_t* B = Bm + (long)z * sBe;
    char* Cb = (char*)Cm + (long)z * sCbBytes;
    const int m0 = by * BM, n0 = bx * BN;
    const int tid = threadIdx.x;
    const int w = tid >> 6, lane = tid & 63;
    const int wm = w >> 2, wn = w & 3;          // 2 x 4 wave grid
    const int l15 = lane & 15, q = lane >> 4;

    f32x4 acc[8][4] = {};

    // staging: half-tile = 256 rows x 32 k (16 KiB) = 16 chunks of 16 rows.
    // lane i: row = chunk*16 + (i>>2); LDS slot = i&3 (linear, gl_lds);
    // GLOBAL slot = (i&3) ^ ((row>>1)&3) = (i&3) ^ ((i>>3)&3)  [T2 pre-swizzle].
    const int srow = w * 16 + (lane >> 2);
    const int skoff = ((lane & 3) ^ ((lane >> 3) & 3)) * 8;
    const ushort_t* Ag = A + (long)(m0 + srow) * lda + skoff;
    const ushort_t* Bg = B + (long)(n0 + srow) * ldb + skoff;
    // T2 read-side key: row = 16*frag + l15 -> (row>>1)&3 == (l15>>1)&3
    const int swk = (l15 >> 1) & 3;

#define STAGE_A(c, h, tk) do { \
    const ushort_t* _g = Ag + (long)(tk) * BKT + (h) * HKK; \
    ushort_t* _l = &lds[(c) * 4 + (h)][w * 512]; \
    gl_lds16(_g, _l); \
    gl_lds16(_g + (long)128 * lda, _l + 4096); } while (0)
#define STAGE_B(c, h, tk) do { \
    const ushort_t* _g = Bg + (long)(tk) * BKT + (h) * HKK; \
    ushort_t* _l = &lds[(c) * 4 + 2 + (h)][w * 512]; \
    gl_lds16(_g, _l); \
    gl_lds16(_g + (long)128 * ldb, _l + 4096); } while (0)
#define RD_A(c, h, mf) (*(const bf16x8*)&lds[(c) * 4 + (h)][(wm * 128 + (mf) * 16 + l15) * HKK + ((q ^ swk) * 8)])
#define RD_B(c, h, nf) (*(const bf16x8*)&lds[(c) * 4 + 2 + (h)][(wn * 64 + (nf) * 16 + l15) * HKK + ((q ^ swk) * 8)])
#define FENCE() asm volatile("" ::: "memory")
#define BARRIER() do { FENCE(); __builtin_amdgcn_s_barrier(); FENCE(); } while (0)
    // reads in MFMA consumption order: af0, bfr0-3, af1..af7 -> compiler's
    // per-use lgkmcnt(N) lets early MFMAs start while later reads drain.
#define READS(c, h) do { \
    af[0] = RD_A(c, h, 0); \
    bfr[0] = RD_B(c, h, 0); bfr[1] = RD_B(c, h, 1); \
    bfr[2] = RD_B(c, h, 2); bfr[3] = RD_B(c, h, 3); \
    _Pragma("unroll") \
    for (int _i = 1; _i < 8; _i++) af[_i] = RD_A(c, h, _i); } while (0)
#define MFMA32() do { \
    __builtin_amdgcn_s_setprio(1); \
    _Pragma("unroll") \
    for (int _i = 0; _i < 8; _i++) \
        _Pragma("unroll") \
        for (int _j = 0; _j < 4; _j++) \
            acc[_i][_j] = __builtin_amdgcn_mfma_f32_16x16x32_bf16( \
                af[_i], bfr[_j], acc[_i][_j], 0, 0, 0); \
    __builtin_amdgcn_s_setprio(0); \
    __builtin_amdgcn_sched_barrier(0); } while (0)

    const int NT = K >> 6;   // K-tiles (NT >= 2 assumed; K in {1024,2048})

    // prologue: tile0 h0+h1 and tile1 h0 (12 loads/wave); vmcnt(4) = tile0 landed
    STAGE_A(0, 0, 0); STAGE_B(0, 0, 0);
    STAGE_A(0, 1, 0); STAGE_B(0, 1, 0);
    STAGE_A(1, 0, 1); STAGE_B(1, 0, 1);
    asm volatile("s_waitcnt vmcnt(4)" ::: "memory");
    BARRIER();

    bf16x8 af[8], bfr[4];
    for (int tk = 0; tk < NT; ++tk) {
        const int c = tk & 1;
        const int pf1 = (tk + 1 < NT), pf2 = (tk + 2 < NT);

        // ---- phase 0: k-half 0, all 8 m-frags; stage (t+1) h1 into c^1 ----
        // ((c^1,h1) reads were serviced before tile t-1's phase-1 end barrier)
        READS(c, 0);
        if (pf1) { STAGE_A(c ^ 1, 1, tk + 1); STAGE_B(c ^ 1, 1, tk + 1); }
        BARRIER();
        MFMA32();
        BARRIER();

        // ---- phase 1: k-half 1; stage (t+2) h0 into c; tile-boundary vmcnt ----
        // ((c,h0) reads were serviced before phase-0's end barrier)
        READS(c, 1);
        if (pf2) { STAGE_A(c, 0, tk + 2); STAGE_B(c, 0, tk + 2); }
        if (tk < NT - 2) asm volatile("s_waitcnt vmcnt(4)" ::: "memory");
        else             asm volatile("s_waitcnt vmcnt(0)" ::: "memory");
        BARRIER();
        MFMA32();
        BARRIER();
    }

    // epilogue: D lane mapping col = lane&15, row = (lane>>4)*4 + r  (m89-verified)
    #pragma unroll
    for (int mf = 0; mf < 8; mf++) {
        #pragma unroll
        for (int r = 0; r < 4; r++) {
            const int row = m0 + wm * 128 + mf * 16 + q * 4 + r;
            #pragma unroll
            for (int nf = 0; nf < 4; nf++) {
                const int col = n0 + wn * 64 + nf * 16 + l15;
                float v = acc[mf][nf][r] * alpha;
                if (epi == 1) v = fmaxf(v, 0.0f);
                else if (epi == 2) v = fmaxf(v, 0.0f) * aux[col];
                else if (epi == 3) v = v + aux[col];
                else if (epi == 4) v = fmaxf(v + aux[col], 0.0f);
                else if (epi == 5) v = v + aux[(long)z * sAuxb + (long)row * ldaux + col];
                if (outF32) ((float*)Cb)[(long)row * ldc + col] = v;
                else        ((ushort_t*)Cb)[(long)row * ldc + col] = f2bf(v);
            }
        }
    }
#undef STAGE_A
#undef STAGE_B
#undef RD_A
#undef RD_B
#undef FENCE
#undef BARRIER
#undef READS
#undef MFMA32
}

// ---------------- elementwise cast f32 -> bf16 (8 elems/thread) ----------------
__global__ __launch_bounds__(256) void cast_f32_bf16_k(
    const float* __restrict__ in, ushort_t* __restrict__ out, int n8)
{
    const int i = blockIdx.x * 256 + threadIdx.x;
    if (i < n8) {
        float4 a = *(const float4*)(in + (long)i * 8);
        float4 b = *(const float4*)(in + (long)i * 8 + 4);
        us8 o;
        o[0] = f2bf(a.x); o[1] = f2bf(a.y); o[2] = f2bf(a.z); o[3] = f2bf(a.w);
        o[4] = f2bf(b.x); o[5] = f2bf(b.y); o[6] = f2bf(b.z); o[7] = f2bf(b.w);
        *(us8*)(out + (long)i * 8) = o;
    }
}

// ---------------- cast-transpose: out[z][c][r] = bf16(in[z][r][c]), in f32 ----------------
__global__ __launch_bounds__(256) void transpose_f32_bf16(
    const float* __restrict__ in, ushort_t* __restrict__ out,
    int R, int Cn, long sIn, long sOut)
{
    __shared__ ushort_t tile[32][33];
    in += (long)blockIdx.z * sIn;
    out += (long)blockIdx.z * sOut;
    const int c0 = blockIdx.x * 32, r0 = blockIdx.y * 32;
    const int tx = threadIdx.x & 31, ty = threadIdx.x >> 5;   // ty 0..7
    #pragma unroll
    for (int i = 0; i < 4; i++)
        tile[ty + i * 8][tx] = f2bf(in[(long)(r0 + ty + i * 8) * Cn + c0 + tx]);
    __syncthreads();
    #pragma unroll
    for (int i = 0; i < 4; i++)
        out[(long)(c0 + ty + i * 8) * R + r0 + tx] = tile[tx][ty + i * 8];
}

// ---------------- row softmax over S (bf16, in place), f32 masks applied ----------------
__global__ __launch_bounds__(256) void softmax_k(
    ushort_t* __restrict__ S, const float* __restrict__ km, const float* __restrict__ qm)
{
    const long row = blockIdx.x;        // 0..B*T-1 ; b = row>>11
    const int b = (int)(row >> 11);
    ushort_t* Sr = S + row * TT;
    const int tid = threadIdx.x;
    us8 sv = *(us8*)(Sr + tid * 8);
    const float* kmr = km + (long)b * TT + tid * 8;
    float4 k0 = *(const float4*)kmr, k1 = *(const float4*)(kmr + 4);
    float kmv[8] = {k0.x, k0.y, k0.z, k0.w, k1.x, k1.y, k1.z, k1.w};
    float v[8];
    #pragma unroll
    for (int j = 0; j < 8; j++)
        v[j] = (kmv[j] == 0.0f) ? NEG_INF_F : bf2f(sv[j]);
    float mx = v[0];
    #pragma unroll
    for (int j = 1; j < 8; j++) mx = fmaxf(mx, v[j]);
    #pragma unroll
    for (int off = 32; off > 0; off >>= 1) mx = fmaxf(mx, __shfl_xor(mx, off));
    __shared__ float red[8];
    if ((tid & 63) == 0) red[tid >> 6] = mx;
    __syncthreads();
    mx = fmaxf(fmaxf(red[0], red[1]), fmaxf(red[2], red[3]));
    float e[8], s = 0.0f;
    #pragma unroll
    for (int j = 0; j < 8; j++) { e[j] = __expf(v[j] - mx); s += e[j]; }
    #pragma unroll
    for (int off = 32; off > 0; off >>= 1) s += __shfl_xor(s, off);
    if ((tid & 63) == 0) red[4 + (tid >> 6)] = s;
    __syncthreads();
    s = red[4] + red[5] + red[6] + red[7];
    const float scale = qm[row] / s;
    us8 o;
    #pragma unroll
    for (int j = 0; j < 8; j++) o[j] = f2bf(e[j] * scale);
    *(us8*)(Sr + tid * 8) = o;   // same addresses this thread read: no hazard
}

// ---------------- LayerNorm rows of (olin_bf16 + resid_f32) -> bf16 ----------------
// residual fused here (r4): removes the 64 MiB f32 aux read from the AV gemm's
// epilogue (r3: that read regressed AV 119->151 us under XCD chunking).
__global__ __launch_bounds__(256) void ln_res_k(
    const ushort_t* __restrict__ olin, const float* __restrict__ resid,
    ushort_t* __restrict__ outp,
    const float* __restrict__ gamma, const float* __restrict__ beta)
{
    const long row = blockIdx.x;
    const ushort_t* xr = olin + row * CC;
    const float* rr = resid + row * CC;
    const int tid = threadIdx.x;
    us4 xq = *(const us4*)(xr + tid * 4);
    float4 rv = *(const float4*)(rr + tid * 4);
    float xs[4] = {bf2f(xq[0]) + rv.x, bf2f(xq[1]) + rv.y,
                   bf2f(xq[2]) + rv.z, bf2f(xq[3]) + rv.w};
    float s = xs[0] + xs[1] + xs[2] + xs[3];
    float ss = xs[0]*xs[0] + xs[1]*xs[1] + xs[2]*xs[2] + xs[3]*xs[3];
    #pragma unroll
    for (int off = 32; off > 0; off >>= 1) { s += __shfl_xor(s, off); ss += __shfl_xor(ss, off); }
    __shared__ float red[8];
    if ((tid & 63) == 0) { red[tid >> 6] = s; red[4 + (tid >> 6)] = ss; }
    __syncthreads();
    s = red[0] + red[1] + red[2] + red[3];
    ss = red[4] + red[5] + red[6] + red[7];
    const float mu = s * (1.0f / CC);
    const float var = ss * (1.0f / CC) - mu * mu;
    const float rstd = rsqrtf(var + 1e-6f);
    float4 gv = *(const float4*)(gamma + tid * 4);
    float4 bv = *(const float4*)(beta + tid * 4);
    float gs[4] = {gv.x, gv.y, gv.z, gv.w}, bs[4] = {bv.x, bv.y, bv.z, bv.w};
    us4 o;
    #pragma unroll
    for (int j = 0; j < 4; j++)
        o[j] = f2bf((xs[j] - mu) * rstd * gs[j] + bs[j]);
    *(us4*)(outp + row * CC + tid * 4) = o;
}

extern "C" void kernel_launch(void* const* d_in, const int* in_sizes, int n_in,
                              void* d_out, int out_size, void* d_ws, size_t ws_size,
                              hipStream_t stream)
{
    // ALL inputs/outputs are FLOAT32.
    const float* queries     = (const float*)d_in[0];
    const float* keys        = (const float*)d_in[1];
    const float* key_masks   = (const float*)d_in[2];
    const float* query_masks = (const float*)d_in[3];
    const float* u           = (const float*)d_in[4];
    const float* dd          = (const float*)d_in[5];
    const float* W1          = (const float*)d_in[6];
    const float* b1          = (const float*)d_in[7];
    const float* W2          = (const float*)d_in[8];
    const float* b2          = (const float*)d_in[9];
    const float* g1          = (const float*)d_in[10];
    const float* be1         = (const float*)d_in[11];

    // ws lifetime-packed into 128 MiB. All internal staging is bf16.
    char* ws = (char*)d_ws;
    const long MiB = 1 << 20;
    ushort_t* f1    = (ushort_t*)(ws + 0 * MiB);
    ushort_t* f2    = (ushort_t*)(ws + 32 * MiB);
    ushort_t* uT    = (ushort_t*)(ws + 64 * MiB);
    ushort_t* Qbf   = (ushort_t*)(ws + 66 * MiB);
    ushort_t* Kbf   = (ushort_t*)(ws + 66 * MiB);
    ushort_t* S     = (ushort_t*)(ws + 64 * MiB);
    ushort_t* keysT = (ushort_t*)(ws + 0 * MiB);    // f1 dead after S-gemm
    ushort_t* olin  = (ushort_t*)(ws + 32 * MiB);   // f2 dead after S-gemm
    ushort_t* W1T   = (ushort_t*)(ws + 0 * MiB);    // keysT dead after AV
    ushort_t* W2T   = (ushort_t*)(ws + 2 * MiB);
    ushort_t* lnb   = (ushort_t*)(ws + 64 * MiB);   // S dead after AV
    ushort_t* hb    = (ushort_t*)(ws + 96 * MiB);
    (void)in_sizes; (void)n_in; (void)out_size; (void)ws_size;

    const int N8 = BB * TT * CC / 8;

    // output 0: queries passthrough (f32, 64 MiB)
    hipMemcpyAsync(d_out, d_in[0], (size_t)BB * TT * CC * sizeof(float),
                   hipMemcpyDeviceToDevice, stream);

    // uT[d][c] = bf16(u[c][d])
    transpose_f32_bf16<<<dim3(CC / 32, CC / 32, 1), 256, 0, stream>>>(u, uT, CC, CC, 0, 0);

    // Qbf = bf16(queries); f1 = relu(Qbf@u) * d_diag[col]
    cast_f32_bf16_k<<<N8 / 256, 256, 0, stream>>>(queries, Qbf, N8);
    gemm_bt<<<dim3(CC / BN, (BB * TT) / BM, 1), 512, 0, stream>>>(
        Qbf, 0, CC, uT, 0, CC, f1, 0, CC, 0, CC, 1.0f, 2, dd, 0, 0, 1);
    // Kbf = bf16(keys) (Qbf dead); f2 = relu(Kbf@u)
    cast_f32_bf16_k<<<N8 / 256, 256, 0, stream>>>(keys, Kbf, N8);
    gemm_bt<<<dim3(CC / BN, (BB * TT) / BM, 1), 512, 0, stream>>>(
        Kbf, 0, CC, uT, 0, CC, f2, 0, CC, 0, CC, 1.0f, 1, nullptr, 0, 0, 1);
    // S[b] = (f1[b] @ f2[b]^T) / 32   (chunked mode: k-window streams from L2)
    gemm_bt<<<dim3(TT / BN, TT / BM, BB), 512, 0, stream>>>(
        f1, (long)TT * CC, CC, f2, (long)TT * CC, CC,
        S, (long)TT * TT * 2, TT, 0, CC, 1.0f / 32.0f, 0, nullptr, 0, 0, 1);
    // softmax rows (key mask -> NEG_INF, multiply by query mask), in place -> P
    softmax_k<<<BB * TT, 256, 0, stream>>>(S, key_masks, query_masks);
    // keysT[b][c][t] = bf16(keys[b][t][c])   (into dead f1 region)
    transpose_f32_bf16<<<dim3(CC / 32, TT / 32, BB), 256, 0, stream>>>(
        keys, keysT, TT, CC, (long)TT * CC, (long)CC * TT);
    // olin[b] = P[b] @ keys[b]   (no residual; linear dispatch mode 0 — r3)
    gemm_bt<<<dim3(CC / BN, TT / BM, BB), 512, 0, stream>>>(
        S, (long)TT * TT, TT, keysT, (long)CC * TT, TT,
        olin, (long)TT * CC * 2, CC, 0, TT, 1.0f, 0, nullptr, 0, 0, 0);
    // W1T/W2T (into dead keysT region)
    transpose_f32_bf16<<<dim3(CC / 32, CC / 32, 1), 256, 0, stream>>>(W1, W1T, CC, CC, 0, 0);
    transpose_f32_bf16<<<dim3(CC / 32, CC / 32, 1), 256, 0, stream>>>(W2, W2T, CC, CC, 0, 0);
    // LayerNorm(olin + queries) -> lnb (residual fused; into dead S region)
    ln_res_k<<<BB * TT, 256, 0, stream>>>(olin, queries, lnb, g1, be1);
    // h = relu(ln @ W1 + b1)
    gemm_bt<<<dim3(CC / BN, (BB * TT) / BM, 1), 512, 0, stream>>>(
        lnb, 0, CC, W1T, 0, CC, hb, 0, CC, 0, CC, 1.0f, 4, b1, 0, 0, 1);
    // out2 = h @ W2 + b2 -> d_out second half, f32
    gemm_bt<<<dim3(CC / BN, (BB * TT) / BM, 1), 512, 0, stream>>>(
        hb, 0, CC, W2T, 0, CC, (float*)d_out + (long)BB * TT * CC, 0, CC, 1,
        CC, 1.0f, 3, b2, 0, 0, 1);
}